// Round 2
// baseline (235.881 us; speedup 1.0000x reference)
//
#include <hip/hip_runtime.h>
#include <hip/hip_bf16.h>
#include <math.h>

typedef __hip_bfloat16 hbf;
typedef __attribute__((ext_vector_type(8))) short short8;
typedef __attribute__((ext_vector_type(4))) short short4v;
typedef __attribute__((ext_vector_type(4))) float f32x4;

#define ROWS 8192
#define SQSL 0.4246609001440095f  // sqrt(SCALE * log2(e)) folded into wq/bqk

__device__ __forceinline__ short f2b(float f) {
    union { hbf h; short s; } u; u.h = __float2bfloat16(f); return u.s;
}
__device__ __forceinline__ float b2f(short s) {
    union { unsigned u; float f; } x;
    x.u = ((unsigned)(unsigned short)s) << 16; return x.f;
}

// ---------------------------------------------------------------------------
// prep (weights only): wq*SQSL, wv, w1c=[W1a | W1b@Wp], w2, bc=b1+W1b@bp.
// bid<64 wq; <128 wv; <384 w1a; <512 w2; <1024 wcomp; else bcomp (1026 blks).
// ---------------------------------------------------------------------------
__global__ __launch_bounds__(256)
void prep(const float* __restrict__ Wqk, const float* __restrict__ Wv,
          const float* __restrict__ Wp, const float* __restrict__ W1,
          const float* __restrict__ W2,
          const float* __restrict__ bp, const float* __restrict__ b1,
          short* __restrict__ wq, short* __restrict__ wv,
          short* __restrict__ w1c, short* __restrict__ w2,
          float* __restrict__ bc)
{
    const int bid = blockIdx.x, tid = threadIdx.x;
    if (bid < 512) {
        const float* src; short* dst; int base; float sc = 1.f;
        if (bid < 64)       { src = Wqk; dst = wq; base = bid;       sc = SQSL; }
        else if (bid < 128) { src = Wv;  dst = wv; base = bid - 64; }
        else if (bid < 384) {
            // W1: keep only cols<256 (W1a) -> w1c[n][0:256]
            int i = (bid - 128) * 256 + tid;
            int n = i >> 7, c = (i & 127) * 4;
            if (c < 256) {
                float4 f = ((const float4*)W1)[i];
                short4v s;
                s[0] = f2b(f.x); s[1] = f2b(f.y); s[2] = f2b(f.z); s[3] = f2b(f.w);
                *(short4v*)(w1c + (size_t)n * 512 + c) = s;
            }
            return;
        }
        else                { src = W2;  dst = w2; base = bid - 384; }
        int i = base * 256 + tid;
        float4 f = ((const float4*)src)[i];
        short4v s;
        s[0] = f2b(f.x * sc); s[1] = f2b(f.y * sc);
        s[2] = f2b(f.z * sc); s[3] = f2b(f.w * sc);
        *(short4v*)(dst + (size_t)i * 4) = s;
    } else if (bid < 1024) {
        int n = bid - 512;
        const float* wrow = W1 + (size_t)n * 512 + 256;
        float acc = 0.f;
        for (int k = 0; k < 256; ++k)
            acc += wrow[k] * Wp[(size_t)k * 256 + tid];
        w1c[(size_t)n * 512 + 256 + tid] = f2b(acc);
    } else {
        int n = (bid - 1024) * 256 + tid;
        const float* wrow = W1 + (size_t)n * 512 + 256;
        float acc = b1[n];
        for (int k = 0; k < 256; ++k) acc += wrow[k] * bp[k];
        bc[n] = acc;
    }
}

// ---------------------------------------------------------------------------
// QKV GEMM v3: direct-fragment loads (no LDS, no barriers in the K loop).
// Each wave loads its own A rows (x, fp32->bf16 in reg) and B rows (weights,
// L2-resident) straight into MFMA fragments with 1-step register double
// buffering. LDS used only for the V-transpose epilogue. XCD swizzle: the 4
// col-blocks of a token-row panel share one XCD's L2.
// ---------------------------------------------------------------------------
__global__ __launch_bounds__(256, 2)
void gemm_qkv(const float* __restrict__ x0, const float* __restrict__ x1,
              const short* __restrict__ Wa, const short* __restrict__ Wb,
              const float* __restrict__ bias0, const float* __restrict__ bias1,
              short* __restrict__ qkb, short* __restrict__ vtb)
{
    const int fid  = blockIdx.x + (blockIdx.y << 2);       // 0..1023
    const int col0 = ((fid >> 3) & 3) * 128;               // id%8 == row octet
    const int row0 = ((fid & 7) + (fid >> 5) * 8) * 64;
    const int tid = threadIdx.x;
    const int lane = tid & 63, wave = tid >> 6;
    const int ln = lane & 15, quad = lane >> 4;
    const int wm = wave & 1, wn = wave >> 1;

    __shared__ short Vt[128 * 72];

    // per-lane A row pointers (x, fp32) and B row pointers (weights, bf16)
    const float* xr[2];
    #pragma unroll
    for (int mi = 0; mi < 2; ++mi) {
        int r = row0 + wm * 32 + mi * 16 + ln;
        xr[mi] = ((r < ROWS) ? x0 + (size_t)r * 256
                             : x1 + (size_t)(r - ROWS) * 256) + quad * 8;
    }
    const short* wbase = (col0 < 256) ? Wa + (size_t)col0 * 256
                                      : Wb + (size_t)(col0 - 256) * 256;
    const short* wr[4];
    #pragma unroll
    for (int nj = 0; nj < 4; ++nj)
        wr[nj] = wbase + (size_t)(wn * 64 + nj * 16 + ln) * 256 + quad * 8;

    f32x4 acc[2][4];
    #pragma unroll
    for (int i = 0; i < 2; ++i)
        #pragma unroll
        for (int j = 0; j < 4; ++j) acc[i][j] = {0.f, 0.f, 0.f, 0.f};

    float4 aB[2][2][2][2];   // [buf][mi][ks][half]
    short8 bB[2][4][2];      // [buf][nj][ks]

    #pragma unroll
    for (int mi = 0; mi < 2; ++mi)
        #pragma unroll
        for (int ks = 0; ks < 2; ++ks) {
            const float* p = xr[mi] + ks * 32;
            aB[0][mi][ks][0] = ((const float4*)p)[0];
            aB[0][mi][ks][1] = ((const float4*)p)[1];
        }
    #pragma unroll
    for (int nj = 0; nj < 4; ++nj)
        #pragma unroll
        for (int ks = 0; ks < 2; ++ks)
            bB[0][nj][ks] = *(const short8*)(wr[nj] + ks * 32);

    #pragma unroll
    for (int kk = 0; kk < 4; ++kk) {
        const int cur = kk & 1, nxt = cur ^ 1;
        if (kk < 3) {
            const int k0 = (kk + 1) * 64;
            #pragma unroll
            for (int mi = 0; mi < 2; ++mi)
                #pragma unroll
                for (int ks = 0; ks < 2; ++ks) {
                    const float* p = xr[mi] + k0 + ks * 32;
                    aB[nxt][mi][ks][0] = ((const float4*)p)[0];
                    aB[nxt][mi][ks][1] = ((const float4*)p)[1];
                }
            #pragma unroll
            for (int nj = 0; nj < 4; ++nj)
                #pragma unroll
                for (int ks = 0; ks < 2; ++ks)
                    bB[nxt][nj][ks] = *(const short8*)(wr[nj] + k0 + ks * 32);
        }
        short8 a[2][2];
        #pragma unroll
        for (int mi = 0; mi < 2; ++mi)
            #pragma unroll
            for (int ks = 0; ks < 2; ++ks) {
                float4 f0 = aB[cur][mi][ks][0], f1 = aB[cur][mi][ks][1];
                short8 s;
                s[0] = f2b(f0.x); s[1] = f2b(f0.y); s[2] = f2b(f0.z); s[3] = f2b(f0.w);
                s[4] = f2b(f1.x); s[5] = f2b(f1.y); s[6] = f2b(f1.z); s[7] = f2b(f1.w);
                a[mi][ks] = s;
            }
        #pragma unroll
        for (int mi = 0; mi < 2; ++mi)
            #pragma unroll
            for (int nj = 0; nj < 4; ++nj) {
                acc[mi][nj] = __builtin_amdgcn_mfma_f32_16x16x32_bf16(
                                  bB[cur][nj][0], a[mi][0], acc[mi][nj], 0, 0, 0);
                acc[mi][nj] = __builtin_amdgcn_mfma_f32_16x16x32_bf16(
                                  bB[cur][nj][1], a[mi][1], acc[mi][nj], 0, 0, 0);
            }
    }

    if (col0 < 256) {
        // QK path: row-major store with SQSL-scaled bias
        #pragma unroll
        for (int nj = 0; nj < 4; ++nj) {
            const int wcol = col0 + wn * 64 + nj * 16 + quad * 4;
            float4 bb = *(const float4*)(bias0 + wcol);
            #pragma unroll
            for (int mi = 0; mi < 2; ++mi) {
                const int tok = row0 + wm * 32 + mi * 16 + ln;
                f32x4 v = acc[mi][nj];
                short4v o;
                o[0] = f2b(fmaf(bb.x, SQSL, v[0]));
                o[1] = f2b(fmaf(bb.y, SQSL, v[1]));
                o[2] = f2b(fmaf(bb.z, SQSL, v[2]));
                o[3] = f2b(fmaf(bb.w, SQSL, v[3]));
                *(short4v*)(qkb + (size_t)tok * 256 + wcol) = o;
            }
        }
    } else {
        // V path: bias add -> LDS transpose -> direct V^T store
        #pragma unroll
        for (int nj = 0; nj < 4; ++nj) {
            const int wrel = wn * 64 + nj * 16 + quad * 4;
            float4 bb = *(const float4*)(bias1 + (col0 - 256) + wrel);
            #pragma unroll
            for (int mi = 0; mi < 2; ++mi) {
                const int tl = wm * 32 + mi * 16 + ln;
                f32x4 v = acc[mi][nj];
                Vt[(wrel + 0) * 72 + tl] = f2b(v[0] + bb.x);
                Vt[(wrel + 1) * 72 + tl] = f2b(v[1] + bb.y);
                Vt[(wrel + 2) * 72 + tl] = f2b(v[2] + bb.z);
                Vt[(wrel + 3) * 72 + tl] = f2b(v[3] + bb.w);
            }
        }
        __syncthreads();
        {
            const int g4 = (row0 >> 11) * 4, tc0 = row0 & 2047;
            const int r = tid >> 1, hf = tid & 1;
            const int vcol = (col0 - 256) + r;          // 0..255
            const int hh = vcol >> 6, d = vcol & 63;
            short* dst = vtb + (size_t)((g4 + hh) * 64 + d) * 2048 + tc0 + hf * 32;
            #pragma unroll
            for (int cc = 0; cc < 4; ++cc)
                *(short8*)(dst + cc * 8) = *(const short8*)&Vt[r * 72 + hf * 32 + cc * 8];
        }
    }
}

// ---------------------------------------------------------------------------
// MFMA flash cross-attention v10: no setprio (r1 regression), no COFF
// (cancels in O/l), v_perm_b32 bf16 pack (1 op vs 3), l accumulated via
// MFMA-against-ones (kills the ss add chain + shfls on the VALU pipe).
// ---------------------------------------------------------------------------
__global__ __launch_bounds__(128, 2)
void attn8(const short* __restrict__ qkb, const short* __restrict__ vtbuf,
           short* __restrict__ pO0, short* __restrict__ pO1,
           float* __restrict__ l0, float* __restrict__ l1)
{
    const int nfl = blockIdx.x + (blockIdx.y << 4) + (blockIdx.z << 8);
    const int qt  = nfl >> 6;               // 0..15
    const int gg  = nfl & 63;               // group: id % 8 == gg % 8 -> XCD
    const int b    = (gg >> 2) & 3, h = gg & 3;
    const int dir  = gg >> 5;
    const int half = (gg >> 4) & 1;
    const int tid = threadIdx.x;
    const int lane = tid & 63, wave = tid >> 6;   // wave 0/1
    const int ln   = lane & 15, quad = lane >> 4;

    const int qbase = dir * ROWS + b * 2048;
    const int kbase = (1 - dir) * ROWS + b * 2048;
    const int vg    = ((1 - dir) * 4 + b) * 4 + h;
    const int jlo   = half * 1024, jhi = jlo + 1024;

    short* __restrict__ pO = half ? pO1 : pO0;
    float* __restrict__ lb = half ? l1  : l0;

    __shared__ short QP[128 * 72];   // Q tile then P tile (per-wave rows)
    __shared__ short KS[64 * 72];
    __shared__ short VT[64 * 72];

    const int c = tid & 7, r0 = tid >> 3;   // r0: 0..15
    #pragma unroll
    for (int g = 0; g < 8; ++g) {
        int r = r0 + g * 16;
        *(short8*)&QP[r * 72 + c * 8] =
            *(const short8*)(qkb + (size_t)(qbase + qt * 128 + r) * 256 + h * 64 + c * 8);
    }
    #pragma unroll
    for (int g = 0; g < 4; ++g) {
        int r = r0 + g * 16;
        *(short8*)&KS[r * 72 + c * 8] =
            *(const short8*)(qkb + (size_t)(kbase + jlo + r) * 256 + h * 64 + c * 8);
        *(short8*)&VT[r * 72 + c * 8] =
            *(const short8*)(vtbuf + (size_t)(vg * 64 + r) * 2048 + jlo + c * 8);
    }
    __syncthreads();

    short8 qf[4][2];
    #pragma unroll
    for (int mi = 0; mi < 4; ++mi)
        #pragma unroll
        for (int ks = 0; ks < 2; ++ks)
            qf[mi][ks] = *(const short8*)&QP[(wave * 64 + mi * 16 + ln) * 72
                                             + ks * 32 + quad * 8];

    short8 ones;
    #pragma unroll
    for (int j = 0; j < 8; ++j) ones[j] = (short)0x3F80;   // bf16 1.0

    f32x4 Ot[4][4];
    #pragma unroll
    for (int mi = 0; mi < 4; ++mi)
        #pragma unroll
        for (int dt = 0; dt < 4; ++dt) Ot[mi][dt] = {0.f, 0.f, 0.f, 0.f};
    f32x4 lacc[4];
    #pragma unroll
    for (int mi = 0; mi < 4; ++mi) lacc[mi] = {0.f, 0.f, 0.f, 0.f};

    for (int j0 = jlo; j0 < jhi; j0 += 64) {
        short8 kreg[4], vreg[4];
        const bool more = (j0 + 64) < jhi;
        if (more) {
            #pragma unroll
            for (int g = 0; g < 4; ++g) {
                int r = r0 + g * 16;
                kreg[g] = *(const short8*)(qkb + (size_t)(kbase + j0 + 64 + r) * 256
                                           + h * 64 + c * 8);
                vreg[g] = *(const short8*)(vtbuf + (size_t)(vg * 64 + r) * 2048
                                           + j0 + 64 + c * 8);
            }
        }

        // S^T = K @ Q^T   (K frags shared across 4 q-subtiles)
        f32x4 St[4][4];
        #pragma unroll
        for (int t = 0; t < 4; ++t) {
            short8 k0 = *(const short8*)&KS[(t * 16 + ln) * 72 + quad * 8];
            short8 k1 = *(const short8*)&KS[(t * 16 + ln) * 72 + 32 + quad * 8];
            #pragma unroll
            for (int mi = 0; mi < 4; ++mi) {
                f32x4 z = {0.f, 0.f, 0.f, 0.f};
                z = __builtin_amdgcn_mfma_f32_16x16x32_bf16(k0, qf[mi][0], z, 0, 0, 0);
                St[mi][t] = __builtin_amdgcn_mfma_f32_16x16x32_bf16(k1, qf[mi][1], z, 0, 0, 0);
            }
        }

        // p = exp2(St); v_perm truncation-pack; P -> own QP rows
        #pragma unroll
        for (int mi = 0; mi < 4; ++mi)
            #pragma unroll
            for (int t = 0; t < 4; ++t) {
                float p0 = __builtin_amdgcn_exp2f(St[mi][t][0]);
                float p1 = __builtin_amdgcn_exp2f(St[mi][t][1]);
                float p2 = __builtin_amdgcn_exp2f(St[mi][t][2]);
                float p3 = __builtin_amdgcn_exp2f(St[mi][t][3]);
                unsigned d0 = __builtin_amdgcn_perm(__float_as_uint(p1),
                                                    __float_as_uint(p0), 0x07060302u);
                unsigned d1 = __builtin_amdgcn_perm(__float_as_uint(p3),
                                                    __float_as_uint(p2), 0x07060302u);
                *(int2*)&QP[(wave * 64 + mi * 16 + ln) * 72 + t * 16 + quad * 4] =
                    make_int2((int)d0, (int)d1);
            }

        // reload P as B-frags; l += 1*P via MFMA; O^T += V^T @ P^T
        short8 pa[4][2];
        #pragma unroll
        for (int mi = 0; mi < 4; ++mi)
            #pragma unroll
            for (int ks = 0; ks < 2; ++ks)
                pa[mi][ks] = *(const short8*)&QP[(wave * 64 + mi * 16 + ln) * 72
                                                 + ks * 32 + quad * 8];
        #pragma unroll
        for (int mi = 0; mi < 4; ++mi) {
            lacc[mi] = __builtin_amdgcn_mfma_f32_16x16x32_bf16(
                           ones, pa[mi][0], lacc[mi], 0, 0, 0);
            lacc[mi] = __builtin_amdgcn_mfma_f32_16x16x32_bf16(
                           ones, pa[mi][1], lacc[mi], 0, 0, 0);
        }
        #pragma unroll
        for (int dt = 0; dt < 4; ++dt) {
            short8 v0 = *(const short8*)&VT[(dt * 16 + ln) * 72 + quad * 8];
            short8 v1 = *(const short8*)&VT[(dt * 16 + ln) * 72 + 32 + quad * 8];
            #pragma unroll
            for (int mi = 0; mi < 4; ++mi) {
                Ot[mi][dt] = __builtin_amdgcn_mfma_f32_16x16x32_bf16(
                                 v0, pa[mi][0], Ot[mi][dt], 0, 0, 0);
                Ot[mi][dt] = __builtin_amdgcn_mfma_f32_16x16x32_bf16(
                                 v1, pa[mi][1], Ot[mi][dt], 0, 0, 0);
            }
        }
        __syncthreads();

        if (more) {
            #pragma unroll
            for (int g = 0; g < 4; ++g) {
                int r = r0 + g * 16;
                *(short8*)&KS[r * 72 + c * 8] = kreg[g];
                *(short8*)&VT[r * 72 + c * 8] = vreg[g];
            }
        }
        __syncthreads();
    }

    #pragma unroll
    for (int mi = 0; mi < 4; ++mi) {
        int tok = qbase + qt * 128 + wave * 64 + mi * 16 + ln;
        if (quad == 0) lb[tok] = lacc[mi][0];
        #pragma unroll
        for (int dt = 0; dt < 4; ++dt) {
            short4v o;
            #pragma unroll
            for (int r = 0; r < 4; ++r) o[r] = f2b(Ot[mi][dt][r]);
            *(short4v*)(pO + (size_t)tok * 256 + h * 64 + dt * 16 + quad * 4) = o;
        }
    }
}

// ---------------------------------------------------------------------------
// Fused MLP v3: B operand loaded DIRECTLY from global (L2-resident weights)
// into MFMA fragments with 1-section register lookahead -> zero barriers in
// both K loops. LDS holds only H ([x|m], then GELU activations). 3 barriers
// total (H ready / LN stats / GELU publish).
// ---------------------------------------------------------------------------
__global__ __launch_bounds__(256, 2)
void mlp_fused(const float* __restrict__ x0, const float* __restrict__ x1,
               const short* __restrict__ pO0, const short* __restrict__ pO1,
               const float* __restrict__ l0, const float* __restrict__ l1,
               const short* __restrict__ w1c, const short* __restrict__ w2,
               const float* __restrict__ bc, const float* __restrict__ gamma,
               const float* __restrict__ beta, const float* __restrict__ b2,
               float* __restrict__ out)
{
    const int tok0 = blockIdx.x * 32;
    const int tid = threadIdx.x;
    const int lane = tid & 63, wave = tid >> 6;
    const int ln = lane & 15, quad = lane >> 4;

    __shared__ short H [32 * 520];    // [x|m] input, later GELU activations
    __shared__ float stats[4][2][32];

    short8 bf[2][8];                  // [buf][nj*2+ks] direct B fragments
    auto loadsec = [&](short8* dst, const short* W, int rowbase, int k0) {
        #pragma unroll
        for (int nj = 0; nj < 4; ++nj)
            #pragma unroll
            for (int ks = 0; ks < 2; ++ks)
                dst[nj * 2 + ks] = *(const short8*)(
                    W + (size_t)(rowbase + nj * 16 + ln) * 512 + k0 + ks * 32 + quad * 8);
    };
    loadsec(bf[0], w1c, wave * 64, 0);   // section s=0 (p=0,k0=0)

    // ---- stage A = [x | m] into H (once) ----
    {
        const int arow = tid >> 3, ac = tid & 7;   // ac: 64-col block
        const int tok = tok0 + arow;
        if (ac < 4) {
            const float* xr = (tok < ROWS ? x0 + (size_t)tok * 256
                                          : x1 + (size_t)(tok - ROWS) * 256) + ac * 64;
            #pragma unroll
            for (int cc = 0; cc < 8; ++cc) {
                float4 f0 = ((const float4*)(xr + cc * 8))[0];
                float4 f1 = ((const float4*)(xr + cc * 8))[1];
                short8 s;
                s[0] = f2b(f0.x); s[1] = f2b(f0.y); s[2] = f2b(f0.z); s[3] = f2b(f0.w);
                s[4] = f2b(f1.x); s[5] = f2b(f1.y); s[6] = f2b(f1.z); s[7] = f2b(f1.w);
                *(short8*)&H[arow * 520 + ac * 64 + cc * 8] = s;
            }
        } else {
            const int vc = (ac - 4) * 64;
            const float inv = __builtin_amdgcn_rcpf(l0[tok] + l1[tok]);
            #pragma unroll
            for (int cc = 0; cc < 8; ++cc) {
                short8 a = *(const short8*)(pO0 + (size_t)tok * 256 + vc + cc * 8);
                short8 b = *(const short8*)(pO1 + (size_t)tok * 256 + vc + cc * 8);
                short8 s;
                #pragma unroll
                for (int j = 0; j < 8; ++j)
                    s[j] = f2b((b2f(a[j]) + b2f(b[j])) * inv);
                *(short8*)&H[arow * 520 + 256 + vc + cc * 8] = s;
            }
        }
    }

    f32x4 acc[2][8];
    #pragma unroll
    for (int i = 0; i < 2; ++i)
        #pragma unroll
        for (int j = 0; j < 8; ++j) acc[i][j] = {0.f, 0.f, 0.f, 0.f};

    __syncthreads();   // H ready

    // ---- phase 1: h = [x|m] @ w1c^T  (16 sections, barrier-free) ----
    short8 a0[2], a1[2];
    #pragma unroll
    for (int s = 0; s < 16; ++s) {
        const int p = s & 1, k0 = (s >> 1) * 64;
        if (p == 0) {
            #pragma unroll
            for (int ks = 0; ks < 2; ++ks) {
                a0[ks] = *(const short8*)&H[ln * 520 + k0 + ks * 32 + quad * 8];
                a1[ks] = *(const short8*)&H[(16 + ln) * 520 + k0 + ks * 32 + quad * 8];
            }
        }
        if (s < 15) {
            const int sn = s + 1;
            loadsec(bf[sn & 1], w1c, (sn & 1) * 256 + wave * 64, (sn >> 1) * 64);
        }
        #pragma unroll
        for (int nj = 0; nj < 4; ++nj)
            #pragma unroll
            for (int ks = 0; ks < 2; ++ks) {
                short8 w = bf[s & 1][nj * 2 + ks];
                acc[0][p * 4 + nj] = __builtin_amdgcn_mfma_f32_16x16x32_bf16(
                                         w, a0[ks], acc[0][p * 4 + nj], 0, 0, 0);
                acc[1][p * 4 + nj] = __builtin_amdgcn_mfma_f32_16x16x32_bf16(
                                         w, a1[ks], acc[1][p * 4 + nj], 0, 0, 0);
            }
    }

    loadsec(bf[0], w2, wave * 64, 0);   // prefetch first w2 section under LN/GELU

    // add bc before LN stats
    #pragma unroll
    for (int p = 0; p < 2; ++p)
        #pragma unroll
        for (int nj = 0; nj < 4; ++nj) {
            int hcol = p * 256 + wave * 64 + nj * 16 + quad * 4;
            float4 bb = *(const float4*)(bc + hcol);
            acc[0][p * 4 + nj][0] += bb.x; acc[1][p * 4 + nj][0] += bb.x;
            acc[0][p * 4 + nj][1] += bb.y; acc[1][p * 4 + nj][1] += bb.y;
            acc[0][p * 4 + nj][2] += bb.z; acc[1][p * 4 + nj][2] += bb.z;
            acc[0][p * 4 + nj][3] += bb.w; acc[1][p * 4 + nj][3] += bb.w;
        }

    // ---- LayerNorm stats ----
    #pragma unroll
    for (int mi = 0; mi < 2; ++mi) {
        float s1 = 0.f, s2 = 0.f;
        #pragma unroll
        for (int j = 0; j < 8; ++j)
            #pragma unroll
            for (int r = 0; r < 4; ++r) {
                float v = acc[mi][j][r];
                s1 += v; s2 += v * v;
            }
        s1 += __shfl_xor(s1, 16); s2 += __shfl_xor(s2, 16);
        s1 += __shfl_xor(s1, 32); s2 += __shfl_xor(s2, 32);
        if (quad == 0) {
            stats[wave][0][mi * 16 + ln] = s1;
            stats[wave][1][mi * 16 + ln] = s2;
        }
    }
    __syncthreads();

    float mean[2], rstd[2];
    #pragma unroll
    for (int mi = 0; mi < 2; ++mi) {
        int t = mi * 16 + ln;
        float s1 = stats[0][0][t] + stats[1][0][t] + stats[2][0][t] + stats[3][0][t];
        float s2 = stats[0][1][t] + stats[1][1][t] + stats[2][1][t] + stats[3][1][t];
        mean[mi] = s1 * (1.f / 512.f);
        float var = s2 * (1.f / 512.f) - mean[mi] * mean[mi];
        rstd[mi] = rsqrtf(var + 1e-5f);
    }

    // ---- GELU -> H ----
    #pragma unroll
    for (int p = 0; p < 2; ++p)
        #pragma unroll
        for (int nj = 0; nj < 4; ++nj) {
            int hcol = p * 256 + wave * 64 + nj * 16 + quad * 4;
            float4 gm = *(const float4*)(gamma + hcol);
            float4 bt = *(const float4*)(beta + hcol);
            #pragma unroll
            for (int mi = 0; mi < 2; ++mi) {
                short4v o;
                #pragma unroll
                for (int r = 0; r < 4; ++r) {
                    float g = (r == 0) ? gm.x : (r == 1) ? gm.y : (r == 2) ? gm.z : gm.w;
                    float bta = (r == 0) ? bt.x : (r == 1) ? bt.y : (r == 2) ? bt.z : bt.w;
                    float y = (acc[mi][p * 4 + nj][r] - mean[mi]) * rstd[mi] * g + bta;
                    float u = y * fmaf(y * y, 0.0356774081f, 0.7978845608f);
                    float e = __builtin_amdgcn_exp2f(u * -2.8853900818f);
                    o[r] = f2b(y * __builtin_amdgcn_rcpf(1.f + e));
                }
                *(short4v*)&H[(mi * 16 + ln) * 520 + hcol] = o;
            }
        }
    __syncthreads();   // GELU H published

    // ---- phase 2: out = H @ w2^T + b2 + x  (8 sections, barrier-free) ----
    f32x4 acc2[2][4];
    #pragma unroll
    for (int i = 0; i < 2; ++i)
        #pragma unroll
        for (int j = 0; j < 4; ++j) acc2[i][j] = {0.f, 0.f, 0.f, 0.f};

    #pragma unroll
    for (int s = 0; s < 8; ++s) {
        const int k0 = s * 64;
        short8 h0[2], h1[2];
        #pragma unroll
        for (int ks = 0; ks < 2; ++ks) {
            h0[ks] = *(const short8*)&H[ln * 520 + k0 + ks * 32 + quad * 8];
            h1[ks] = *(const short8*)&H[(16 + ln) * 520 + k0 + ks * 32 + quad * 8];
        }
        if (s < 7) loadsec(bf[(s + 1) & 1], w2, wave * 64, k0 + 64);
        #pragma unroll
        for (int nj = 0; nj < 4; ++nj)
            #pragma unroll
            for (int ks = 0; ks < 2; ++ks) {
                short8 w = bf[s & 1][nj * 2 + ks];
                acc2[0][nj] = __builtin_amdgcn_mfma_f32_16x16x32_bf16(
                                  w, h0[ks], acc2[0][nj], 0, 0, 0);
                acc2[1][nj] = __builtin_amdgcn_mfma_f32_16x16x32_bf16(
                                  w, h1[ks], acc2[1][nj], 0, 0, 0);
            }
    }

    #pragma unroll
    for (int nj = 0; nj < 4; ++nj) {
        int ocol = wave * 64 + nj * 16 + quad * 4;
        float4 bb = *(const float4*)(b2 + ocol);
        #pragma unroll
        for (int mi = 0; mi < 2; ++mi) {
            int tok = tok0 + mi * 16 + ln;
            const float* xr = (tok < ROWS ? x0 + (size_t)tok * 256
                                          : x1 + (size_t)(tok - ROWS) * 256);
            float4 rv = *(const float4*)(xr + ocol);
            float4 o;
            o.x = acc2[mi][nj][0] + bb.x + rv.x;
            o.y = acc2[mi][nj][1] + bb.y + rv.y;
            o.z = acc2[mi][nj][2] + bb.z + rv.z;
            o.w = acc2[mi][nj][3] + bb.w + rv.w;
            *(float4*)(out + (size_t)tok * 256 + ocol) = o;
        }
    }
}

// ---------------------------------------------------------------------------
extern "C" void kernel_launch(void* const* d_in, const int* in_sizes, int n_in,
                              void* d_out, int out_size, void* d_ws, size_t ws_size,
                              hipStream_t stream)
{
    const float* x0    = (const float*)d_in[0];
    const float* x1    = (const float*)d_in[1];
    const float* Wqk   = (const float*)d_in[2];
    const float* bqk   = (const float*)d_in[3];
    const float* Wv    = (const float*)d_in[4];
    const float* bv    = (const float*)d_in[5];
    const float* Wp    = (const float*)d_in[6];
    const float* bp    = (const float*)d_in[7];
    const float* W1    = (const float*)d_in[8];
    const float* b1    = (const float*)d_in[9];
    const float* gamma = (const float*)d_in[10];
    const float* beta  = (const float*)d_in[11];
    const float* W2    = (const float*)d_in[12];
    const float* b2    = (const float*)d_in[13];
    float* out = (float*)d_out;

    char* ws = (char*)d_ws;
    const size_t MB = 1024 * 1024;
    short* qkb  = (short*)ws;                    // [0,8)
    short* vtb  = (short*)(ws + 8  * MB);        // [8,16)
    short* pO0  = (short*)(ws + 16 * MB);        // [16,24)
    short* pO1  = (short*)(ws + 24 * MB);        // [24,32)
    float* l0   = (float*)(ws + 32 * MB);
    float* l1   = l0 + 16384;
    float* bc   = l1 + 16384;
    short* wq   = (short*)(bc + 512);
    short* wv   = wq + 65536;
    short* w1c  = wv + 65536;                    // [512,512]
    short* w2   = w1c + 262144;                  // [256,512]

    prep<<<1026, 256, 0, stream>>>(Wqk, Wv, Wp, W1, W2, bp, b1,
                                   wq, wv, w1c, w2, bc);
    gemm_qkv<<<dim3(4, 256), 256, 0, stream>>>(x0, x1, wq, wv, bqk, bv, qkb, vtb);
    attn8<<<dim3(16, 16, 4), 128, 0, stream>>>(qkb, vtb, pO0, pO1, l0, l1);
    mlp_fused<<<512, 256, 0, stream>>>(x0, x1, pO0, pO1, l0, l1, w1c, w2, bc,
                                       gamma, beta, b2, out);
}

// Round 3
// 196.549 us; speedup vs baseline: 1.2001x; 1.2001x over previous
//
#include <hip/hip_runtime.h>
#include <hip/hip_bf16.h>
#include <math.h>

typedef __hip_bfloat16 hbf;
typedef __attribute__((ext_vector_type(8))) short short8;
typedef __attribute__((ext_vector_type(4))) short short4v;
typedef __attribute__((ext_vector_type(4))) float f32x4;

#define ROWS 8192
#define SQSL 0.4246609001440095f  // sqrt(SCALE * log2(e)) folded into wq/bqk

__device__ __forceinline__ short f2b(float f) {
    union { hbf h; short s; } u; u.h = __float2bfloat16(f); return u.s;
}
__device__ __forceinline__ float b2f(short s) {
    union { unsigned u; float f; } x;
    x.u = ((unsigned)(unsigned short)s) << 16; return x.f;
}

// ---------------------------------------------------------------------------
// prep (weights only): wq*SQSL, wv, w1c=[W1a | W1b@Wp], w2, bc=b1+W1b@bp.
// bid<64 wq; <128 wv; <384 w1a; <512 w2; <1024 wcomp; else bcomp (1026 blks).
// ---------------------------------------------------------------------------
__global__ __launch_bounds__(256)
void prep(const float* __restrict__ Wqk, const float* __restrict__ Wv,
          const float* __restrict__ Wp, const float* __restrict__ W1,
          const float* __restrict__ W2,
          const float* __restrict__ bp, const float* __restrict__ b1,
          short* __restrict__ wq, short* __restrict__ wv,
          short* __restrict__ w1c, short* __restrict__ w2,
          float* __restrict__ bc)
{
    const int bid = blockIdx.x, tid = threadIdx.x;
    if (bid < 512) {
        const float* src; short* dst; int base; float sc = 1.f;
        if (bid < 64)       { src = Wqk; dst = wq; base = bid;       sc = SQSL; }
        else if (bid < 128) { src = Wv;  dst = wv; base = bid - 64; }
        else if (bid < 384) {
            // W1: keep only cols<256 (W1a) -> w1c[n][0:256]
            int i = (bid - 128) * 256 + tid;
            int n = i >> 7, c = (i & 127) * 4;
            if (c < 256) {
                float4 f = ((const float4*)W1)[i];
                short4v s;
                s[0] = f2b(f.x); s[1] = f2b(f.y); s[2] = f2b(f.z); s[3] = f2b(f.w);
                *(short4v*)(w1c + (size_t)n * 512 + c) = s;
            }
            return;
        }
        else                { src = W2;  dst = w2; base = bid - 384; }
        int i = base * 256 + tid;
        float4 f = ((const float4*)src)[i];
        short4v s;
        s[0] = f2b(f.x * sc); s[1] = f2b(f.y * sc);
        s[2] = f2b(f.z * sc); s[3] = f2b(f.w * sc);
        *(short4v*)(dst + (size_t)i * 4) = s;
    } else if (bid < 1024) {
        int n = bid - 512;
        const float* wrow = W1 + (size_t)n * 512 + 256;
        float acc = 0.f;
        for (int k = 0; k < 256; ++k)
            acc += wrow[k] * Wp[(size_t)k * 256 + tid];
        w1c[(size_t)n * 512 + 256 + tid] = f2b(acc);
    } else {
        int n = (bid - 1024) * 256 + tid;
        const float* wrow = W1 + (size_t)n * 512 + 256;
        float acc = b1[n];
        for (int k = 0; k < 256; ++k) acc += wrow[k] * bp[k];
        bc[n] = acc;
    }
}

// ---------------------------------------------------------------------------
// QKV GEMM v2 (r1 measured-good): 64 tok x 128 wcol block, 4 waves x (2x4),
// BK=64 LDS-staged with reg double-buffer. QK blocks write qkb row-major;
// V blocks transpose in-LDS and write V^T directly (vtrans fused).
// ---------------------------------------------------------------------------
__global__ __launch_bounds__(256)
void gemm_qkv(const float* __restrict__ x0, const float* __restrict__ x1,
              const short* __restrict__ Wa, const short* __restrict__ Wb,
              const float* __restrict__ bias0, const float* __restrict__ bias1,
              short* __restrict__ qkb, short* __restrict__ vtb)
{
    const int fid  = blockIdx.x + (blockIdx.y << 2);   // 0..1023
    const int col0 = (fid >> 8) * 128;                 // XCD = fid%8 ~ row group
    const int row0 = (fid & 255) * 64;
    const int tid = threadIdx.x;
    const int lane = tid & 63, wave = tid >> 6;
    const int ln = lane & 15, quad = lane >> 4;
    const int wm = wave & 1, wn = wave >> 1;

    __shared__ short smem[64 * 72 + 128 * 72];
    short* As = smem;                 // [64][72]
    short* Bs = smem + 64 * 72;       // [128][72]
    short* Vt = smem;                 // epilogue reuse: [128][72] (V blocks)

    const int ar = tid >> 2, ac = tid & 3;   // ar 0..63, ac: 16-col chunk

    f32x4 acc[2][4];
    #pragma unroll
    for (int i = 0; i < 2; ++i)
        #pragma unroll
        for (int j = 0; j < 4; ++j) acc[i][j] = {0.f, 0.f, 0.f, 0.f};

    const short* wbase = (col0 < 256) ? Wa + (size_t)col0 * 256
                                      : Wb + (size_t)(col0 - 256) * 256;
    const float* xrow = (row0 + ar < ROWS)
        ? x0 + (size_t)(row0 + ar) * 256
        : x1 + (size_t)(row0 + ar - ROWS) * 256;

    float4 aF[4];
    short8 bR[4];
    #pragma unroll
    for (int i = 0; i < 4; ++i) aF[i] = ((const float4*)(xrow + ac * 16))[i];
    bR[0] = *(const short8*)(wbase + (size_t)ar * 256 + ac * 16);
    bR[1] = *(const short8*)(wbase + (size_t)ar * 256 + ac * 16 + 8);
    bR[2] = *(const short8*)(wbase + (size_t)(ar + 64) * 256 + ac * 16);
    bR[3] = *(const short8*)(wbase + (size_t)(ar + 64) * 256 + ac * 16 + 8);

    for (int k0 = 0; k0 < 256; k0 += 64) {
        {
            short8 s0, s1;
            s0[0] = f2b(aF[0].x); s0[1] = f2b(aF[0].y); s0[2] = f2b(aF[0].z); s0[3] = f2b(aF[0].w);
            s0[4] = f2b(aF[1].x); s0[5] = f2b(aF[1].y); s0[6] = f2b(aF[1].z); s0[7] = f2b(aF[1].w);
            s1[0] = f2b(aF[2].x); s1[1] = f2b(aF[2].y); s1[2] = f2b(aF[2].z); s1[3] = f2b(aF[2].w);
            s1[4] = f2b(aF[3].x); s1[5] = f2b(aF[3].y); s1[6] = f2b(aF[3].z); s1[7] = f2b(aF[3].w);
            *(short8*)&As[ar * 72 + ac * 16]     = s0;
            *(short8*)&As[ar * 72 + ac * 16 + 8] = s1;
        }
        *(short8*)&Bs[ar * 72 + ac * 16]            = bR[0];
        *(short8*)&Bs[ar * 72 + ac * 16 + 8]        = bR[1];
        *(short8*)&Bs[(ar + 64) * 72 + ac * 16]     = bR[2];
        *(short8*)&Bs[(ar + 64) * 72 + ac * 16 + 8] = bR[3];
        __syncthreads();

        if (k0 + 64 < 256) {
            const int kk = k0 + 64 + ac * 16;
            #pragma unroll
            for (int i = 0; i < 4; ++i) aF[i] = ((const float4*)(xrow + kk))[i];
            bR[0] = *(const short8*)(wbase + (size_t)ar * 256 + kk);
            bR[1] = *(const short8*)(wbase + (size_t)ar * 256 + kk + 8);
            bR[2] = *(const short8*)(wbase + (size_t)(ar + 64) * 256 + kk);
            bR[3] = *(const short8*)(wbase + (size_t)(ar + 64) * 256 + kk + 8);
        }

        short8 a[2][2], b[4][2];
        #pragma unroll
        for (int mi = 0; mi < 2; ++mi)
            #pragma unroll
            for (int ks = 0; ks < 2; ++ks)
                a[mi][ks] = *(const short8*)&As[(wm * 32 + mi * 16 + ln) * 72 + ks * 32 + quad * 8];
        #pragma unroll
        for (int nj = 0; nj < 4; ++nj)
            #pragma unroll
            for (int ks = 0; ks < 2; ++ks)
                b[nj][ks] = *(const short8*)&Bs[(wn * 64 + nj * 16 + ln) * 72 + ks * 32 + quad * 8];
        #pragma unroll
        for (int mi = 0; mi < 2; ++mi)
            #pragma unroll
            for (int nj = 0; nj < 4; ++nj) {
                acc[mi][nj] = __builtin_amdgcn_mfma_f32_16x16x32_bf16(
                                  b[nj][0], a[mi][0], acc[mi][nj], 0, 0, 0);
                acc[mi][nj] = __builtin_amdgcn_mfma_f32_16x16x32_bf16(
                                  b[nj][1], a[mi][1], acc[mi][nj], 0, 0, 0);
            }
        __syncthreads();
    }

    if (col0 < 256) {
        // QK path: row-major store with SQSL-scaled bias
        #pragma unroll
        for (int nj = 0; nj < 4; ++nj) {
            const int wcol = col0 + wn * 64 + nj * 16 + quad * 4;
            float4 bb = *(const float4*)(bias0 + wcol);
            #pragma unroll
            for (int mi = 0; mi < 2; ++mi) {
                const int tok = row0 + wm * 32 + mi * 16 + ln;
                f32x4 v = acc[mi][nj];
                short4v o;
                o[0] = f2b(fmaf(bb.x, SQSL, v[0]));
                o[1] = f2b(fmaf(bb.y, SQSL, v[1]));
                o[2] = f2b(fmaf(bb.z, SQSL, v[2]));
                o[3] = f2b(fmaf(bb.w, SQSL, v[3]));
                *(short4v*)(qkb + (size_t)tok * 256 + wcol) = o;
            }
        }
    } else {
        // V path: bias add -> LDS transpose -> direct V^T store (vtrans fused)
        #pragma unroll
        for (int nj = 0; nj < 4; ++nj) {
            const int wrel = wn * 64 + nj * 16 + quad * 4;
            float4 bb = *(const float4*)(bias1 + (col0 - 256) + wrel);
            #pragma unroll
            for (int mi = 0; mi < 2; ++mi) {
                const int tl = wm * 32 + mi * 16 + ln;
                f32x4 v = acc[mi][nj];
                Vt[(wrel + 0) * 72 + tl] = f2b(v[0] + bb.x);
                Vt[(wrel + 1) * 72 + tl] = f2b(v[1] + bb.y);
                Vt[(wrel + 2) * 72 + tl] = f2b(v[2] + bb.z);
                Vt[(wrel + 3) * 72 + tl] = f2b(v[3] + bb.w);
            }
        }
        __syncthreads();
        {
            const int g4 = (row0 >> 11) * 4, tc0 = row0 & 2047;
            const int r = tid >> 1, hf = tid & 1;
            const int vcol = (col0 - 256) + r;          // 0..255
            const int hh = vcol >> 6, d = vcol & 63;
            short* dst = vtb + (size_t)((g4 + hh) * 64 + d) * 2048 + tc0 + hf * 32;
            #pragma unroll
            for (int cc = 0; cc < 4; ++cc)
                *(short8*)(dst + cc * 8) = *(const short8*)&Vt[r * 72 + hf * 32 + cc * 8];
        }
    }
}

// ---------------------------------------------------------------------------
// MFMA flash cross-attention v10 (kept from r2 -- measured better than v9):
// no setprio, no COFF (cancels in O/l), v_perm_b32 bf16 pack,
// l accumulated via MFMA-against-ones.
// ---------------------------------------------------------------------------
__global__ __launch_bounds__(128, 2)
void attn8(const short* __restrict__ qkb, const short* __restrict__ vtbuf,
           short* __restrict__ pO0, short* __restrict__ pO1,
           float* __restrict__ l0, float* __restrict__ l1)
{
    const int nfl = blockIdx.x + (blockIdx.y << 4) + (blockIdx.z << 8);
    const int qt  = nfl >> 6;               // 0..15
    const int gg  = nfl & 63;               // group: id % 8 == gg % 8 -> XCD
    const int b    = (gg >> 2) & 3, h = gg & 3;
    const int dir  = gg >> 5;
    const int half = (gg >> 4) & 1;
    const int tid = threadIdx.x;
    const int lane = tid & 63, wave = tid >> 6;   // wave 0/1
    const int ln   = lane & 15, quad = lane >> 4;

    const int qbase = dir * ROWS + b * 2048;
    const int kbase = (1 - dir) * ROWS + b * 2048;
    const int vg    = ((1 - dir) * 4 + b) * 4 + h;
    const int jlo   = half * 1024, jhi = jlo + 1024;

    short* __restrict__ pO = half ? pO1 : pO0;
    float* __restrict__ lb = half ? l1  : l0;

    __shared__ short QP[128 * 72];   // Q tile then P tile (per-wave rows)
    __shared__ short KS[64 * 72];
    __shared__ short VT[64 * 72];

    const int c = tid & 7, r0 = tid >> 3;   // r0: 0..15
    #pragma unroll
    for (int g = 0; g < 8; ++g) {
        int r = r0 + g * 16;
        *(short8*)&QP[r * 72 + c * 8] =
            *(const short8*)(qkb + (size_t)(qbase + qt * 128 + r) * 256 + h * 64 + c * 8);
    }
    #pragma unroll
    for (int g = 0; g < 4; ++g) {
        int r = r0 + g * 16;
        *(short8*)&KS[r * 72 + c * 8] =
            *(const short8*)(qkb + (size_t)(kbase + jlo + r) * 256 + h * 64 + c * 8);
        *(short8*)&VT[r * 72 + c * 8] =
            *(const short8*)(vtbuf + (size_t)(vg * 64 + r) * 2048 + jlo + c * 8);
    }
    __syncthreads();

    short8 qf[4][2];
    #pragma unroll
    for (int mi = 0; mi < 4; ++mi)
        #pragma unroll
        for (int ks = 0; ks < 2; ++ks)
            qf[mi][ks] = *(const short8*)&QP[(wave * 64 + mi * 16 + ln) * 72
                                             + ks * 32 + quad * 8];

    short8 ones;
    #pragma unroll
    for (int j = 0; j < 8; ++j) ones[j] = (short)0x3F80;   // bf16 1.0

    f32x4 Ot[4][4];
    #pragma unroll
    for (int mi = 0; mi < 4; ++mi)
        #pragma unroll
        for (int dt = 0; dt < 4; ++dt) Ot[mi][dt] = {0.f, 0.f, 0.f, 0.f};
    f32x4 lacc[4];
    #pragma unroll
    for (int mi = 0; mi < 4; ++mi) lacc[mi] = {0.f, 0.f, 0.f, 0.f};

    for (int j0 = jlo; j0 < jhi; j0 += 64) {
        short8 kreg[4], vreg[4];
        const bool more = (j0 + 64) < jhi;
        if (more) {
            #pragma unroll
            for (int g = 0; g < 4; ++g) {
                int r = r0 + g * 16;
                kreg[g] = *(const short8*)(qkb + (size_t)(kbase + j0 + 64 + r) * 256
                                           + h * 64 + c * 8);
                vreg[g] = *(const short8*)(vtbuf + (size_t)(vg * 64 + r) * 2048
                                           + j0 + 64 + c * 8);
            }
        }

        // S^T = K @ Q^T   (K frags shared across 4 q-subtiles)
        f32x4 St[4][4];
        #pragma unroll
        for (int t = 0; t < 4; ++t) {
            short8 k0 = *(const short8*)&KS[(t * 16 + ln) * 72 + quad * 8];
            short8 k1 = *(const short8*)&KS[(t * 16 + ln) * 72 + 32 + quad * 8];
            #pragma unroll
            for (int mi = 0; mi < 4; ++mi) {
                f32x4 z = {0.f, 0.f, 0.f, 0.f};
                z = __builtin_amdgcn_mfma_f32_16x16x32_bf16(k0, qf[mi][0], z, 0, 0, 0);
                St[mi][t] = __builtin_amdgcn_mfma_f32_16x16x32_bf16(k1, qf[mi][1], z, 0, 0, 0);
            }
        }

        // p = exp2(St); v_perm truncation-pack; P -> own QP rows
        #pragma unroll
        for (int mi = 0; mi < 4; ++mi)
            #pragma unroll
            for (int t = 0; t < 4; ++t) {
                float p0 = __builtin_amdgcn_exp2f(St[mi][t][0]);
                float p1 = __builtin_amdgcn_exp2f(St[mi][t][1]);
                float p2 = __builtin_amdgcn_exp2f(St[mi][t][2]);
                float p3 = __builtin_amdgcn_exp2f(St[mi][t][3]);
                unsigned d0 = __builtin_amdgcn_perm(__float_as_uint(p1),
                                                    __float_as_uint(p0), 0x07060302u);
                unsigned d1 = __builtin_amdgcn_perm(__float_as_uint(p3),
                                                    __float_as_uint(p2), 0x07060302u);
                *(int2*)&QP[(wave * 64 + mi * 16 + ln) * 72 + t * 16 + quad * 4] =
                    make_int2((int)d0, (int)d1);
            }

        // reload P as B-frags; l += 1*P via MFMA; O^T += V^T @ P^T
        short8 pa[4][2];
        #pragma unroll
        for (int mi = 0; mi < 4; ++mi)
            #pragma unroll
            for (int ks = 0; ks < 2; ++ks)
                pa[mi][ks] = *(const short8*)&QP[(wave * 64 + mi * 16 + ln) * 72
                                                 + ks * 32 + quad * 8];
        #pragma unroll
        for (int mi = 0; mi < 4; ++mi) {
            lacc[mi] = __builtin_amdgcn_mfma_f32_16x16x32_bf16(
                           ones, pa[mi][0], lacc[mi], 0, 0, 0);
            lacc[mi] = __builtin_amdgcn_mfma_f32_16x16x32_bf16(
                           ones, pa[mi][1], lacc[mi], 0, 0, 0);
        }
        #pragma unroll
        for (int dt = 0; dt < 4; ++dt) {
            short8 v0 = *(const short8*)&VT[(dt * 16 + ln) * 72 + quad * 8];
            short8 v1 = *(const short8*)&VT[(dt * 16 + ln) * 72 + 32 + quad * 8];
            #pragma unroll
            for (int mi = 0; mi < 4; ++mi) {
                Ot[mi][dt] = __builtin_amdgcn_mfma_f32_16x16x32_bf16(
                                 v0, pa[mi][0], Ot[mi][dt], 0, 0, 0);
                Ot[mi][dt] = __builtin_amdgcn_mfma_f32_16x16x32_bf16(
                                 v1, pa[mi][1], Ot[mi][dt], 0, 0, 0);
            }
        }
        __syncthreads();

        if (more) {
            #pragma unroll
            for (int g = 0; g < 4; ++g) {
                int r = r0 + g * 16;
                *(short8*)&KS[r * 72 + c * 8] = kreg[g];
                *(short8*)&VT[r * 72 + c * 8] = vreg[g];
            }
        }
        __syncthreads();
    }

    #pragma unroll
    for (int mi = 0; mi < 4; ++mi) {
        int tok = qbase + qt * 128 + wave * 64 + mi * 16 + ln;
        if (quad == 0) lb[tok] = lacc[mi][0];
        #pragma unroll
        for (int dt = 0; dt < 4; ++dt) {
            short4v o;
            #pragma unroll
            for (int r = 0; r < 4; ++r) o[r] = f2b(Ot[mi][dt][r]);
            *(short4v*)(pO + (size_t)tok * 256 + h * 64 + dt * 16 + quad * 4) = o;
        }
    }
}

// ---------------------------------------------------------------------------
// Fused MLP v2 (r1 measured-good): [x|m] staged ONCE into H, BK=64 in both
// phases, B-tile register prefetch through LDS bounce.
// ---------------------------------------------------------------------------
__global__ __launch_bounds__(256)
void mlp_fused(const float* __restrict__ x0, const float* __restrict__ x1,
               const short* __restrict__ pO0, const short* __restrict__ pO1,
               const float* __restrict__ l0, const float* __restrict__ l1,
               const short* __restrict__ w1c, const short* __restrict__ w2,
               const float* __restrict__ bc, const float* __restrict__ gamma,
               const float* __restrict__ beta, const float* __restrict__ b2,
               float* __restrict__ out)
{
    const int tok0 = blockIdx.x * 32;
    const int tid = threadIdx.x;
    const int lane = tid & 63, wave = tid >> 6;
    const int ln = lane & 15, quad = lane >> 4;

    __shared__ short H [32 * 520];    // [x|m] input, later GELU activations
    __shared__ short Bs[256 * 72];    // weight K-panel (both phases)
    __shared__ float stats[4][2][32];

    const int br = tid >> 2, bq = tid & 3;
    short8 bp[8];
    auto loadB = [&](const short* W, int rw, int k0) {
        const short* src = W + (size_t)(rw + br) * 512 + k0 + bq * 16;
        #pragma unroll
        for (int q = 0; q < 4; ++q) {
            bp[2 * q]     = *(const short8*)(src + (size_t)q * 64 * 512);
            bp[2 * q + 1] = *(const short8*)(src + (size_t)q * 64 * 512 + 8);
        }
    };
    loadB(w1c, 0, 0);   // section (k2=0, p=0)

    // ---- stage A = [x | m] into H (once) ----
    {
        const int arow = tid >> 3, ac = tid & 7;   // ac: 64-col block
        const int tok = tok0 + arow;
        if (ac < 4) {
            const float* xr = (tok < ROWS ? x0 + (size_t)tok * 256
                                          : x1 + (size_t)(tok - ROWS) * 256) + ac * 64;
            #pragma unroll
            for (int cc = 0; cc < 8; ++cc) {
                float4 f0 = ((const float4*)(xr + cc * 8))[0];
                float4 f1 = ((const float4*)(xr + cc * 8))[1];
                short8 s;
                s[0] = f2b(f0.x); s[1] = f2b(f0.y); s[2] = f2b(f0.z); s[3] = f2b(f0.w);
                s[4] = f2b(f1.x); s[5] = f2b(f1.y); s[6] = f2b(f1.z); s[7] = f2b(f1.w);
                *(short8*)&H[arow * 520 + ac * 64 + cc * 8] = s;
            }
        } else {
            const int vc = (ac - 4) * 64;
            const float inv = __builtin_amdgcn_rcpf(l0[tok] + l1[tok]);
            #pragma unroll
            for (int cc = 0; cc < 8; ++cc) {
                short8 a = *(const short8*)(pO0 + (size_t)tok * 256 + vc + cc * 8);
                short8 b = *(const short8*)(pO1 + (size_t)tok * 256 + vc + cc * 8);
                short8 s;
                #pragma unroll
                for (int j = 0; j < 8; ++j)
                    s[j] = f2b((b2f(a[j]) + b2f(b[j])) * inv);
                *(short8*)&H[arow * 520 + 256 + vc + cc * 8] = s;
            }
        }
    }

    f32x4 acc[2][8];
    #pragma unroll
    for (int i = 0; i < 2; ++i)
        #pragma unroll
        for (int j = 0; j < 8; ++j) acc[i][j] = {0.f, 0.f, 0.f, 0.f};

    __syncthreads();   // H ready

    // ---- phase 1: h = [x|m] @ w1c^T ----
    for (int k2 = 0; k2 < 8; ++k2) {
        const int k0 = k2 * 64;
        short8 a0[2], a1[2];
        #pragma unroll
        for (int ks = 0; ks < 2; ++ks) {
            a0[ks] = *(const short8*)&H[ln * 520 + k0 + ks * 32 + quad * 8];
            a1[ks] = *(const short8*)&H[(16 + ln) * 520 + k0 + ks * 32 + quad * 8];
        }
        #pragma unroll
        for (int p = 0; p < 2; ++p) {
            #pragma unroll
            for (int q = 0; q < 4; ++q) {
                *(short8*)&Bs[(br + q * 64) * 72 + bq * 16]     = bp[2 * q];
                *(short8*)&Bs[(br + q * 64) * 72 + bq * 16 + 8] = bp[2 * q + 1];
            }
            __syncthreads();
            if (p == 0)          loadB(w1c, 256, k0);
            else if (k2 < 7)     loadB(w1c, 0, k0 + 64);
            #pragma unroll
            for (int nj = 0; nj < 4; ++nj) {
                #pragma unroll
                for (int ks = 0; ks < 2; ++ks) {
                    short8 bf = *(const short8*)&Bs[(wave * 64 + nj * 16 + ln) * 72
                                                    + ks * 32 + quad * 8];
                    acc[0][p * 4 + nj] = __builtin_amdgcn_mfma_f32_16x16x32_bf16(
                                             bf, a0[ks], acc[0][p * 4 + nj], 0, 0, 0);
                    acc[1][p * 4 + nj] = __builtin_amdgcn_mfma_f32_16x16x32_bf16(
                                             bf, a1[ks], acc[1][p * 4 + nj], 0, 0, 0);
                }
            }
            __syncthreads();
        }
    }

    loadB(w2, 0, 0);   // prefetch first w2 panel under LN/GELU

    // add bc before LN stats
    #pragma unroll
    for (int p = 0; p < 2; ++p)
        #pragma unroll
        for (int nj = 0; nj < 4; ++nj) {
            int hcol = p * 256 + wave * 64 + nj * 16 + quad * 4;
            float4 bb = *(const float4*)(bc + hcol);
            acc[0][p * 4 + nj][0] += bb.x; acc[1][p * 4 + nj][0] += bb.x;
            acc[0][p * 4 + nj][1] += bb.y; acc[1][p * 4 + nj][1] += bb.y;
            acc[0][p * 4 + nj][2] += bb.z; acc[1][p * 4 + nj][2] += bb.z;
            acc[0][p * 4 + nj][3] += bb.w; acc[1][p * 4 + nj][3] += bb.w;
        }

    // ---- LayerNorm stats ----
    #pragma unroll
    for (int mi = 0; mi < 2; ++mi) {
        float s1 = 0.f, s2 = 0.f;
        #pragma unroll
        for (int j = 0; j < 8; ++j)
            #pragma unroll
            for (int r = 0; r < 4; ++r) {
                float v = acc[mi][j][r];
                s1 += v; s2 += v * v;
            }
        s1 += __shfl_xor(s1, 16); s2 += __shfl_xor(s2, 16);
        s1 += __shfl_xor(s1, 32); s2 += __shfl_xor(s2, 32);
        if (quad == 0) {
            stats[wave][0][mi * 16 + ln] = s1;
            stats[wave][1][mi * 16 + ln] = s2;
        }
    }
    __syncthreads();

    float mean[2], rstd[2];
    #pragma unroll
    for (int mi = 0; mi < 2; ++mi) {
        int t = mi * 16 + ln;
        float s1 = stats[0][0][t] + stats[1][0][t] + stats[2][0][t] + stats[3][0][t];
        float s2 = stats[0][1][t] + stats[1][1][t] + stats[2][1][t] + stats[3][1][t];
        mean[mi] = s1 * (1.f / 512.f);
        float var = s2 * (1.f / 512.f) - mean[mi] * mean[mi];
        rstd[mi] = rsqrtf(var + 1e-5f);
    }

    // ---- GELU -> H ----
    #pragma unroll
    for (int p = 0; p < 2; ++p)
        #pragma unroll
        for (int nj = 0; nj < 4; ++nj) {
            int hcol = p * 256 + wave * 64 + nj * 16 + quad * 4;
            float4 gm = *(const float4*)(gamma + hcol);
            float4 bt = *(const float4*)(beta + hcol);
            #pragma unroll
            for (int mi = 0; mi < 2; ++mi) {
                short4v o;
                #pragma unroll
                for (int r = 0; r < 4; ++r) {
                    float g = (r == 0) ? gm.x : (r == 1) ? gm.y : (r == 2) ? gm.z : gm.w;
                    float bta = (r == 0) ? bt.x : (r == 1) ? bt.y : (r == 2) ? bt.z : bt.w;
                    float y = (acc[mi][p * 4 + nj][r] - mean[mi]) * rstd[mi] * g + bta;
                    float u = y * fmaf(y * y, 0.0356774081f, 0.7978845608f);
                    float e = __builtin_amdgcn_exp2f(u * -2.8853900818f);
                    o[r] = f2b(y * __builtin_amdgcn_rcpf(1.f + e));
                }
                *(short4v*)&H[(mi * 16 + ln) * 520 + hcol] = o;
            }
        }

    // ---- phase 2: out = H @ w2^T + b2 + x ----
    f32x4 acc2[2][4];
    #pragma unroll
    for (int i = 0; i < 2; ++i)
        #pragma unroll
        for (int j = 0; j < 4; ++j) acc2[i][j] = {0.f, 0.f, 0.f, 0.f};

    for (int s = 0; s < 8; ++s) {
        const int k0 = s * 64;
        #pragma unroll
        for (int q = 0; q < 4; ++q) {
            *(short8*)&Bs[(br + q * 64) * 72 + bq * 16]     = bp[2 * q];
            *(short8*)&Bs[(br + q * 64) * 72 + bq * 16 + 8] = bp[2 * q + 1];
        }
        __syncthreads();   // also publishes GELU H on s==0
        if (s < 7) loadB(w2, 0, k0 + 64);
        short8 h0[2], h1[2];
        #pragma unroll
        for (int ks = 0; ks < 2; ++ks) {
            h0[ks] = *(const short8*)&H[ln * 520 + k0 + ks * 32 + quad * 8];
            h1[ks] = *(const short8*)&H[(16 + ln) * 520 + k0 + ks * 32 + quad * 8];
        }
        #pragma unroll
        for (int nj = 0; nj < 4; ++nj) {
            #pragma unroll
            for (int ks = 0; ks < 2; ++ks) {
                short8 wf = *(const short8*)&Bs[(wave * 64 + nj * 16 + ln) * 72
                                                + ks * 32 + quad * 8];
                acc2[0][nj] = __builtin_amdgcn_mfma_f32_16x16x32_bf16(
                                  wf, h0[ks], acc2[0][nj], 0, 0, 0);
                acc2[1][nj] = __builtin_amdgcn_mfma_f32_16x16x32_bf16(
                                  wf, h1[ks], acc2[1][nj], 0, 0, 0);
            }
        }
        __syncthreads();
    }

    #pragma unroll
    for (int nj = 0; nj < 4; ++nj) {
        int ocol = wave * 64 + nj * 16 + quad * 4;
        float4 bb = *(const float4*)(b2 + ocol);
        #pragma unroll
        for (int mi = 0; mi < 2; ++mi) {
            int tok = tok0 + mi * 16 + ln;
            const float* xr = (tok < ROWS ? x0 + (size_t)tok * 256
                                          : x1 + (size_t)(tok - ROWS) * 256);
            float4 rv = *(const float4*)(xr + ocol);
            float4 o;
            o.x = acc2[mi][nj][0] + bb.x + rv.x;
            o.y = acc2[mi][nj][1] + bb.y + rv.y;
            o.z = acc2[mi][nj][2] + bb.z + rv.z;
            o.w = acc2[mi][nj][3] + bb.w + rv.w;
            *(float4*)(out + (size_t)tok * 256 + ocol) = o;
        }
    }
}

// ---------------------------------------------------------------------------
extern "C" void kernel_launch(void* const* d_in, const int* in_sizes, int n_in,
                              void* d_out, int out_size, void* d_ws, size_t ws_size,
                              hipStream_t stream)
{
    const float* x0    = (const float*)d_in[0];
    const float* x1    = (const float*)d_in[1];
    const float* Wqk   = (const float*)d_in[2];
    const float* bqk   = (const float*)d_in[3];
    const float* Wv    = (const float*)d_in[4];
    const float* bv    = (const float*)d_in[5];
    const float* Wp    = (const float*)d_in[6];
    const float* bp    = (const float*)d_in[7];
    const float* W1    = (const float*)d_in[8];
    const float* b1    = (const float*)d_in[9];
    const float* gamma = (const float*)d_in[10];
    const float* beta  = (const float*)d_in[11];
    const float* W2    = (const float*)d_in[12];
    const float* b2    = (const float*)d_in[13];
    float* out = (float*)d_out;

    char* ws = (char*)d_ws;
    const size_t MB = 1024 * 1024;
    short* qkb  = (short*)ws;                    // [0,8)
    short* vtb  = (short*)(ws + 8  * MB);        // [8,16)
    short* pO0  = (short*)(ws + 16 * MB);        // [16,24)
    short* pO1  = (short*)(ws + 24 * MB);        // [24,32)
    float* l0   = (float*)(ws + 32 * MB);
    float* l1   = l0 + 16384;
    float* bc   = l1 + 16384;
    short* wq   = (short*)(bc + 512);
    short* wv   = wq + 65536;
    short* w1c  = wv + 65536;                    // [512,512]
    short* w2   = w1c + 262144;                  // [256,512]

    prep<<<1026, 256, 0, stream>>>(Wqk, Wv, Wp, W1, W2, bp, b1,
                                   wq, wv, w1c, w2, bc);
    gemm_qkv<<<dim3(4, 256), 256, 0, stream>>>(x0, x1, wq, wv, bqk, bv, qkb, vtb);
    attn8<<<dim3(16, 16, 4), 128, 0, stream>>>(qkb, vtb, pO0, pO1, l0, l1);
    mlp_fused<<<512, 256, 0, stream>>>(x0, x1, pO0, pO1, l0, l1, w1c, w2, bc,
                                       gamma, beta, b2, out);
}

// Round 4
// 195.352 us; speedup vs baseline: 1.2075x; 1.0061x over previous
//
#include <hip/hip_runtime.h>
#include <hip/hip_bf16.h>
#include <math.h>

typedef __hip_bfloat16 hbf;
typedef __attribute__((ext_vector_type(8))) short short8;
typedef __attribute__((ext_vector_type(4))) short short4v;
typedef __attribute__((ext_vector_type(4))) float f32x4;

#define ROWS 8192
#define SQSL 0.4246609001440095f  // sqrt(SCALE * log2(e)) folded into wq/bqk

__device__ __forceinline__ short f2b(float f) {
    union { hbf h; short s; } u; u.h = __float2bfloat16(f); return u.s;
}
__device__ __forceinline__ float b2f(short s) {
    union { unsigned u; float f; } x;
    x.u = ((unsigned)(unsigned short)s) << 16; return x.f;
}

// ---------------------------------------------------------------------------
// prep (weights only): wq*SQSL, wv, w1c=[W1a | W1b@Wp], w2, bc=b1+W1b@bp.
// bid<64 wq; <128 wv; <384 w1a; <512 w2; <1024 wcomp; else bcomp (1026 blks).
// ---------------------------------------------------------------------------
__global__ __launch_bounds__(256)
void prep(const float* __restrict__ Wqk, const float* __restrict__ Wv,
          const float* __restrict__ Wp, const float* __restrict__ W1,
          const float* __restrict__ W2,
          const float* __restrict__ bp, const float* __restrict__ b1,
          short* __restrict__ wq, short* __restrict__ wv,
          short* __restrict__ w1c, short* __restrict__ w2,
          float* __restrict__ bc)
{
    const int bid = blockIdx.x, tid = threadIdx.x;
    if (bid < 512) {
        const float* src; short* dst; int base; float sc = 1.f;
        if (bid < 64)       { src = Wqk; dst = wq; base = bid;       sc = SQSL; }
        else if (bid < 128) { src = Wv;  dst = wv; base = bid - 64; }
        else if (bid < 384) {
            // W1: keep only cols<256 (W1a) -> w1c[n][0:256]
            int i = (bid - 128) * 256 + tid;
            int n = i >> 7, c = (i & 127) * 4;
            if (c < 256) {
                float4 f = ((const float4*)W1)[i];
                short4v s;
                s[0] = f2b(f.x); s[1] = f2b(f.y); s[2] = f2b(f.z); s[3] = f2b(f.w);
                *(short4v*)(w1c + (size_t)n * 512 + c) = s;
            }
            return;
        }
        else                { src = W2;  dst = w2; base = bid - 384; }
        int i = base * 256 + tid;
        float4 f = ((const float4*)src)[i];
        short4v s;
        s[0] = f2b(f.x * sc); s[1] = f2b(f.y * sc);
        s[2] = f2b(f.z * sc); s[3] = f2b(f.w * sc);
        *(short4v*)(dst + (size_t)i * 4) = s;
    } else if (bid < 1024) {
        int n = bid - 512;
        const float* wrow = W1 + (size_t)n * 512 + 256;
        float acc = 0.f;
        for (int k = 0; k < 256; ++k)
            acc += wrow[k] * Wp[(size_t)k * 256 + tid];
        w1c[(size_t)n * 512 + 256 + tid] = f2b(acc);
    } else {
        int n = (bid - 1024) * 256 + tid;
        const float* wrow = W1 + (size_t)n * 512 + 256;
        float acc = b1[n];
        for (int k = 0; k < 256; ++k) acc += wrow[k] * bp[k];
        bc[n] = acc;
    }
}

// ---------------------------------------------------------------------------
// QKV GEMM v2 (r1 measured-good): 64 tok x 128 wcol block, 4 waves x (2x4),
// BK=64 LDS-staged with reg double-buffer. QK blocks write qkb row-major;
// V blocks transpose in-LDS and write V^T directly (vtrans fused).
// ---------------------------------------------------------------------------
__global__ __launch_bounds__(256)
void gemm_qkv(const float* __restrict__ x0, const float* __restrict__ x1,
              const short* __restrict__ Wa, const short* __restrict__ Wb,
              const float* __restrict__ bias0, const float* __restrict__ bias1,
              short* __restrict__ qkb, short* __restrict__ vtb)
{
    const int fid  = blockIdx.x + (blockIdx.y << 2);   // 0..1023
    const int col0 = (fid >> 8) * 128;                 // XCD = fid%8 ~ row group
    const int row0 = (fid & 255) * 64;
    const int tid = threadIdx.x;
    const int lane = tid & 63, wave = tid >> 6;
    const int ln = lane & 15, quad = lane >> 4;
    const int wm = wave & 1, wn = wave >> 1;

    __shared__ short smem[64 * 72 + 128 * 72];
    short* As = smem;                 // [64][72]
    short* Bs = smem + 64 * 72;       // [128][72]
    short* Vt = smem;                 // epilogue reuse: [128][72] (V blocks)

    const int ar = tid >> 2, ac = tid & 3;   // ar 0..63, ac: 16-col chunk

    f32x4 acc[2][4];
    #pragma unroll
    for (int i = 0; i < 2; ++i)
        #pragma unroll
        for (int j = 0; j < 4; ++j) acc[i][j] = {0.f, 0.f, 0.f, 0.f};

    const short* wbase = (col0 < 256) ? Wa + (size_t)col0 * 256
                                      : Wb + (size_t)(col0 - 256) * 256;
    const float* xrow = (row0 + ar < ROWS)
        ? x0 + (size_t)(row0 + ar) * 256
        : x1 + (size_t)(row0 + ar - ROWS) * 256;

    float4 aF[4];
    short8 bR[4];
    #pragma unroll
    for (int i = 0; i < 4; ++i) aF[i] = ((const float4*)(xrow + ac * 16))[i];
    bR[0] = *(const short8*)(wbase + (size_t)ar * 256 + ac * 16);
    bR[1] = *(const short8*)(wbase + (size_t)ar * 256 + ac * 16 + 8);
    bR[2] = *(const short8*)(wbase + (size_t)(ar + 64) * 256 + ac * 16);
    bR[3] = *(const short8*)(wbase + (size_t)(ar + 64) * 256 + ac * 16 + 8);

    for (int k0 = 0; k0 < 256; k0 += 64) {
        {
            short8 s0, s1;
            s0[0] = f2b(aF[0].x); s0[1] = f2b(aF[0].y); s0[2] = f2b(aF[0].z); s0[3] = f2b(aF[0].w);
            s0[4] = f2b(aF[1].x); s0[5] = f2b(aF[1].y); s0[6] = f2b(aF[1].z); s0[7] = f2b(aF[1].w);
            s1[0] = f2b(aF[2].x); s1[1] = f2b(aF[2].y); s1[2] = f2b(aF[2].z); s1[3] = f2b(aF[2].w);
            s1[4] = f2b(aF[3].x); s1[5] = f2b(aF[3].y); s1[6] = f2b(aF[3].z); s1[7] = f2b(aF[3].w);
            *(short8*)&As[ar * 72 + ac * 16]     = s0;
            *(short8*)&As[ar * 72 + ac * 16 + 8] = s1;
        }
        *(short8*)&Bs[ar * 72 + ac * 16]            = bR[0];
        *(short8*)&Bs[ar * 72 + ac * 16 + 8]        = bR[1];
        *(short8*)&Bs[(ar + 64) * 72 + ac * 16]     = bR[2];
        *(short8*)&Bs[(ar + 64) * 72 + ac * 16 + 8] = bR[3];
        __syncthreads();

        if (k0 + 64 < 256) {
            const int kk = k0 + 64 + ac * 16;
            #pragma unroll
            for (int i = 0; i < 4; ++i) aF[i] = ((const float4*)(xrow + kk))[i];
            bR[0] = *(const short8*)(wbase + (size_t)ar * 256 + kk);
            bR[1] = *(const short8*)(wbase + (size_t)ar * 256 + kk + 8);
            bR[2] = *(const short8*)(wbase + (size_t)(ar + 64) * 256 + kk);
            bR[3] = *(const short8*)(wbase + (size_t)(ar + 64) * 256 + kk + 8);
        }

        short8 a[2][2], b[4][2];
        #pragma unroll
        for (int mi = 0; mi < 2; ++mi)
            #pragma unroll
            for (int ks = 0; ks < 2; ++ks)
                a[mi][ks] = *(const short8*)&As[(wm * 32 + mi * 16 + ln) * 72 + ks * 32 + quad * 8];
        #pragma unroll
        for (int nj = 0; nj < 4; ++nj)
            #pragma unroll
            for (int ks = 0; ks < 2; ++ks)
                b[nj][ks] = *(const short8*)&Bs[(wn * 64 + nj * 16 + ln) * 72 + ks * 32 + quad * 8];
        #pragma unroll
        for (int mi = 0; mi < 2; ++mi)
            #pragma unroll
            for (int nj = 0; nj < 4; ++nj) {
                acc[mi][nj] = __builtin_amdgcn_mfma_f32_16x16x32_bf16(
                                  b[nj][0], a[mi][0], acc[mi][nj], 0, 0, 0);
                acc[mi][nj] = __builtin_amdgcn_mfma_f32_16x16x32_bf16(
                                  b[nj][1], a[mi][1], acc[mi][nj], 0, 0, 0);
            }
        __syncthreads();
    }

    if (col0 < 256) {
        // QK path: row-major store with SQSL-scaled bias
        #pragma unroll
        for (int nj = 0; nj < 4; ++nj) {
            const int wcol = col0 + wn * 64 + nj * 16 + quad * 4;
            float4 bb = *(const float4*)(bias0 + wcol);
            #pragma unroll
            for (int mi = 0; mi < 2; ++mi) {
                const int tok = row0 + wm * 32 + mi * 16 + ln;
                f32x4 v = acc[mi][nj];
                short4v o;
                o[0] = f2b(fmaf(bb.x, SQSL, v[0]));
                o[1] = f2b(fmaf(bb.y, SQSL, v[1]));
                o[2] = f2b(fmaf(bb.z, SQSL, v[2]));
                o[3] = f2b(fmaf(bb.w, SQSL, v[3]));
                *(short4v*)(qkb + (size_t)tok * 256 + wcol) = o;
            }
        }
    } else {
        // V path: bias add -> LDS transpose -> direct V^T store (vtrans fused)
        #pragma unroll
        for (int nj = 0; nj < 4; ++nj) {
            const int wrel = wn * 64 + nj * 16 + quad * 4;
            float4 bb = *(const float4*)(bias1 + (col0 - 256) + wrel);
            #pragma unroll
            for (int mi = 0; mi < 2; ++mi) {
                const int tl = wm * 32 + mi * 16 + ln;
                f32x4 v = acc[mi][nj];
                Vt[(wrel + 0) * 72 + tl] = f2b(v[0] + bb.x);
                Vt[(wrel + 1) * 72 + tl] = f2b(v[1] + bb.y);
                Vt[(wrel + 2) * 72 + tl] = f2b(v[2] + bb.z);
                Vt[(wrel + 3) * 72 + tl] = f2b(v[3] + bb.w);
            }
        }
        __syncthreads();
        {
            const int g4 = (row0 >> 11) * 4, tc0 = row0 & 2047;
            const int r = tid >> 1, hf = tid & 1;
            const int vcol = (col0 - 256) + r;          // 0..255
            const int hh = vcol >> 6, d = vcol & 63;
            short* dst = vtb + (size_t)((g4 + hh) * 64 + d) * 2048 + tc0 + hf * 32;
            #pragma unroll
            for (int cc = 0; cc < 4; ++cc)
                *(short8*)(dst + cc * 8) = *(const short8*)&Vt[r * 72 + hf * 32 + cc * 8];
        }
    }
}

// ---------------------------------------------------------------------------
// MFMA flash cross-attention v11: 4 waves x 32 q-rows (was 2 x 64) -> 16
// waves/CU resident (2x occupancy; r3 counter showed 15.6% as the limiter).
// Q frags load direct global->reg (L2-resident, one-time). Same v10 softmax:
// no COFF, v_perm pack, l via MFMA-against-ones. LDS unchanged: 36.9 KB.
// ---------------------------------------------------------------------------
__global__ __launch_bounds__(256, 4)
void attn8(const short* __restrict__ qkb, const short* __restrict__ vtbuf,
           short* __restrict__ pO0, short* __restrict__ pO1,
           float* __restrict__ l0, float* __restrict__ l1)
{
    const int nfl = blockIdx.x + (blockIdx.y << 4) + (blockIdx.z << 8);
    const int qt  = nfl >> 6;               // 0..15
    const int gg  = nfl & 63;               // group: id % 8 == gg % 8 -> XCD
    const int b    = (gg >> 2) & 3, h = gg & 3;
    const int dir  = gg >> 5;
    const int half = (gg >> 4) & 1;
    const int tid = threadIdx.x;
    const int lane = tid & 63, wave = tid >> 6;   // wave 0..3
    const int ln   = lane & 15, quad = lane >> 4;

    const int qbase = dir * ROWS + b * 2048;
    const int kbase = (1 - dir) * ROWS + b * 2048;
    const int vg    = ((1 - dir) * 4 + b) * 4 + h;
    const int jlo   = half * 1024, jhi = jlo + 1024;

    short* __restrict__ pO = half ? pO1 : pO0;
    float* __restrict__ lb = half ? l1  : l0;

    __shared__ short QP[128 * 72];   // P tile (per-wave 32-row bands)
    __shared__ short KS[64 * 72];
    __shared__ short VT[64 * 72];

    const int c = tid & 7, r0 = tid >> 3;   // r0: 0..31
    #pragma unroll
    for (int g = 0; g < 2; ++g) {
        int r = r0 + g * 32;
        *(short8*)&KS[r * 72 + c * 8] =
            *(const short8*)(qkb + (size_t)(kbase + jlo + r) * 256 + h * 64 + c * 8);
        *(short8*)&VT[r * 72 + c * 8] =
            *(const short8*)(vtbuf + (size_t)(vg * 64 + r) * 2048 + jlo + c * 8);
    }

    // Q fragments: direct global->reg (row per lane, 16B chunks, L2-resident)
    short8 qf[2][2];
    #pragma unroll
    for (int mi = 0; mi < 2; ++mi)
        #pragma unroll
        for (int ks = 0; ks < 2; ++ks)
            qf[mi][ks] = *(const short8*)(
                qkb + (size_t)(qbase + qt * 128 + wave * 32 + mi * 16 + ln) * 256
                + h * 64 + ks * 32 + quad * 8);

    short8 ones;
    #pragma unroll
    for (int j = 0; j < 8; ++j) ones[j] = (short)0x3F80;   // bf16 1.0

    f32x4 Ot[2][4];
    #pragma unroll
    for (int mi = 0; mi < 2; ++mi)
        #pragma unroll
        for (int dt = 0; dt < 4; ++dt) Ot[mi][dt] = {0.f, 0.f, 0.f, 0.f};
    f32x4 lacc[2];
    #pragma unroll
    for (int mi = 0; mi < 2; ++mi) lacc[mi] = {0.f, 0.f, 0.f, 0.f};

    __syncthreads();

    for (int j0 = jlo; j0 < jhi; j0 += 64) {
        short8 kreg[2], vreg[2];
        const bool more = (j0 + 64) < jhi;
        if (more) {
            #pragma unroll
            for (int g = 0; g < 2; ++g) {
                int r = r0 + g * 32;
                kreg[g] = *(const short8*)(qkb + (size_t)(kbase + j0 + 64 + r) * 256
                                           + h * 64 + c * 8);
                vreg[g] = *(const short8*)(vtbuf + (size_t)(vg * 64 + r) * 2048
                                           + j0 + 64 + c * 8);
            }
        }

        // S^T = K @ Q^T   (K frags shared across 2 q-subtiles)
        f32x4 St[2][4];
        #pragma unroll
        for (int t = 0; t < 4; ++t) {
            short8 k0 = *(const short8*)&KS[(t * 16 + ln) * 72 + quad * 8];
            short8 k1 = *(const short8*)&KS[(t * 16 + ln) * 72 + 32 + quad * 8];
            #pragma unroll
            for (int mi = 0; mi < 2; ++mi) {
                f32x4 z = {0.f, 0.f, 0.f, 0.f};
                z = __builtin_amdgcn_mfma_f32_16x16x32_bf16(k0, qf[mi][0], z, 0, 0, 0);
                St[mi][t] = __builtin_amdgcn_mfma_f32_16x16x32_bf16(k1, qf[mi][1], z, 0, 0, 0);
            }
        }

        // p = exp2(St); v_perm truncation-pack; P -> own QP rows
        #pragma unroll
        for (int mi = 0; mi < 2; ++mi)
            #pragma unroll
            for (int t = 0; t < 4; ++t) {
                float p0 = __builtin_amdgcn_exp2f(St[mi][t][0]);
                float p1 = __builtin_amdgcn_exp2f(St[mi][t][1]);
                float p2 = __builtin_amdgcn_exp2f(St[mi][t][2]);
                float p3 = __builtin_amdgcn_exp2f(St[mi][t][3]);
                unsigned d0 = __builtin_amdgcn_perm(__float_as_uint(p1),
                                                    __float_as_uint(p0), 0x07060302u);
                unsigned d1 = __builtin_amdgcn_perm(__float_as_uint(p3),
                                                    __float_as_uint(p2), 0x07060302u);
                *(int2*)&QP[(wave * 32 + mi * 16 + ln) * 72 + t * 16 + quad * 4] =
                    make_int2((int)d0, (int)d1);
            }

        // reload P as B-frags; l += 1*P via MFMA; O^T += V^T @ P^T
        short8 pa[2][2];
        #pragma unroll
        for (int mi = 0; mi < 2; ++mi)
            #pragma unroll
            for (int ks = 0; ks < 2; ++ks)
                pa[mi][ks] = *(const short8*)&QP[(wave * 32 + mi * 16 + ln) * 72
                                                 + ks * 32 + quad * 8];
        #pragma unroll
        for (int mi = 0; mi < 2; ++mi) {
            lacc[mi] = __builtin_amdgcn_mfma_f32_16x16x32_bf16(
                           ones, pa[mi][0], lacc[mi], 0, 0, 0);
            lacc[mi] = __builtin_amdgcn_mfma_f32_16x16x32_bf16(
                           ones, pa[mi][1], lacc[mi], 0, 0, 0);
        }
        #pragma unroll
        for (int dt = 0; dt < 4; ++dt) {
            short8 v0 = *(const short8*)&VT[(dt * 16 + ln) * 72 + quad * 8];
            short8 v1 = *(const short8*)&VT[(dt * 16 + ln) * 72 + 32 + quad * 8];
            #pragma unroll
            for (int mi = 0; mi < 2; ++mi) {
                Ot[mi][dt] = __builtin_amdgcn_mfma_f32_16x16x32_bf16(
                                 v0, pa[mi][0], Ot[mi][dt], 0, 0, 0);
                Ot[mi][dt] = __builtin_amdgcn_mfma_f32_16x16x32_bf16(
                                 v1, pa[mi][1], Ot[mi][dt], 0, 0, 0);
            }
        }
        __syncthreads();

        if (more) {
            #pragma unroll
            for (int g = 0; g < 2; ++g) {
                int r = r0 + g * 32;
                *(short8*)&KS[r * 72 + c * 8] = kreg[g];
                *(short8*)&VT[r * 72 + c * 8] = vreg[g];
            }
        }
        __syncthreads();
    }

    #pragma unroll
    for (int mi = 0; mi < 2; ++mi) {
        int tok = qbase + qt * 128 + wave * 32 + mi * 16 + ln;
        if (quad == 0) lb[tok] = lacc[mi][0];
        #pragma unroll
        for (int dt = 0; dt < 4; ++dt) {
            short4v o;
            #pragma unroll
            for (int r = 0; r < 4; ++r) o[r] = f2b(Ot[mi][dt][r]);
            *(short4v*)(pO + (size_t)tok * 256 + h * 64 + dt * 16 + quad * 4) = o;
        }
    }
}

// ---------------------------------------------------------------------------
// Fused MLP v2 (r1 measured-good): [x|m] staged ONCE into H, BK=64 in both
// phases, B-tile register prefetch through LDS bounce.
// ---------------------------------------------------------------------------
__global__ __launch_bounds__(256)
void mlp_fused(const float* __restrict__ x0, const float* __restrict__ x1,
               const short* __restrict__ pO0, const short* __restrict__ pO1,
               const float* __restrict__ l0, const float* __restrict__ l1,
               const short* __restrict__ w1c, const short* __restrict__ w2,
               const float* __restrict__ bc, const float* __restrict__ gamma,
               const float* __restrict__ beta, const float* __restrict__ b2,
               float* __restrict__ out)
{
    const int tok0 = blockIdx.x * 32;
    const int tid = threadIdx.x;
    const int lane = tid & 63, wave = tid >> 6;
    const int ln = lane & 15, quad = lane >> 4;

    __shared__ short H [32 * 520];    // [x|m] input, later GELU activations
    __shared__ short Bs[256 * 72];    // weight K-panel (both phases)
    __shared__ float stats[4][2][32];

    const int br = tid >> 2, bq = tid & 3;
    short8 bp[8];
    auto loadB = [&](const short* W, int rw, int k0) {
        const short* src = W + (size_t)(rw + br) * 512 + k0 + bq * 16;
        #pragma unroll
        for (int q = 0; q < 4; ++q) {
            bp[2 * q]     = *(const short8*)(src + (size_t)q * 64 * 512);
            bp[2 * q + 1] = *(const short8*)(src + (size_t)q * 64 * 512 + 8);
        }
    };
    loadB(w1c, 0, 0);   // section (k2=0, p=0)

    // ---- stage A = [x | m] into H (once) ----
    {
        const int arow = tid >> 3, ac = tid & 7;   // ac: 64-col block
        const int tok = tok0 + arow;
        if (ac < 4) {
            const float* xr = (tok < ROWS ? x0 + (size_t)tok * 256
                                          : x1 + (size_t)(tok - ROWS) * 256) + ac * 64;
            #pragma unroll
            for (int cc = 0; cc < 8; ++cc) {
                float4 f0 = ((const float4*)(xr + cc * 8))[0];
                float4 f1 = ((const float4*)(xr + cc * 8))[1];
                short8 s;
                s[0] = f2b(f0.x); s[1] = f2b(f0.y); s[2] = f2b(f0.z); s[3] = f2b(f0.w);
                s[4] = f2b(f1.x); s[5] = f2b(f1.y); s[6] = f2b(f1.z); s[7] = f2b(f1.w);
                *(short8*)&H[arow * 520 + ac * 64 + cc * 8] = s;
            }
        } else {
            const int vc = (ac - 4) * 64;
            const float inv = __builtin_amdgcn_rcpf(l0[tok] + l1[tok]);
            #pragma unroll
            for (int cc = 0; cc < 8; ++cc) {
                short8 a = *(const short8*)(pO0 + (size_t)tok * 256 + vc + cc * 8);
                short8 b = *(const short8*)(pO1 + (size_t)tok * 256 + vc + cc * 8);
                short8 s;
                #pragma unroll
                for (int j = 0; j < 8; ++j)
                    s[j] = f2b((b2f(a[j]) + b2f(b[j])) * inv);
                *(short8*)&H[arow * 520 + 256 + vc + cc * 8] = s;
            }
        }
    }

    f32x4 acc[2][8];
    #pragma unroll
    for (int i = 0; i < 2; ++i)
        #pragma unroll
        for (int j = 0; j < 8; ++j) acc[i][j] = {0.f, 0.f, 0.f, 0.f};

    __syncthreads();   // H ready

    // ---- phase 1: h = [x|m] @ w1c^T ----
    for (int k2 = 0; k2 < 8; ++k2) {
        const int k0 = k2 * 64;
        short8 a0[2], a1[2];
        #pragma unroll
        for (int ks = 0; ks < 2; ++ks) {
            a0[ks] = *(const short8*)&H[ln * 520 + k0 + ks * 32 + quad * 8];
            a1[ks] = *(const short8*)&H[(16 + ln) * 520 + k0 + ks * 32 + quad * 8];
        }
        #pragma unroll
        for (int p = 0; p < 2; ++p) {
            #pragma unroll
            for (int q = 0; q < 4; ++q) {
                *(short8*)&Bs[(br + q * 64) * 72 + bq * 16]     = bp[2 * q];
                *(short8*)&Bs[(br + q * 64) * 72 + bq * 16 + 8] = bp[2 * q + 1];
            }
            __syncthreads();
            if (p == 0)          loadB(w1c, 256, k0);
            else if (k2 < 7)     loadB(w1c, 0, k0 + 64);
            #pragma unroll
            for (int nj = 0; nj < 4; ++nj) {
                #pragma unroll
                for (int ks = 0; ks < 2; ++ks) {
                    short8 bf = *(const short8*)&Bs[(wave * 64 + nj * 16 + ln) * 72
                                                    + ks * 32 + quad * 8];
                    acc[0][p * 4 + nj] = __builtin_amdgcn_mfma_f32_16x16x32_bf16(
                                             bf, a0[ks], acc[0][p * 4 + nj], 0, 0, 0);
                    acc[1][p * 4 + nj] = __builtin_amdgcn_mfma_f32_16x16x32_bf16(
                                             bf, a1[ks], acc[1][p * 4 + nj], 0, 0, 0);
                }
            }
            __syncthreads();
        }
    }

    loadB(w2, 0, 0);   // prefetch first w2 panel under LN/GELU

    // add bc before LN stats
    #pragma unroll
    for (int p = 0; p < 2; ++p)
        #pragma unroll
        for (int nj = 0; nj < 4; ++nj) {
            int hcol = p * 256 + wave * 64 + nj * 16 + quad * 4;
            float4 bb = *(const float4*)(bc + hcol);
            acc[0][p * 4 + nj][0] += bb.x; acc[1][p * 4 + nj][0] += bb.x;
            acc[0][p * 4 + nj][1] += bb.y; acc[1][p * 4 + nj][1] += bb.y;
            acc[0][p * 4 + nj][2] += bb.z; acc[1][p * 4 + nj][2] += bb.z;
            acc[0][p * 4 + nj][3] += bb.w; acc[1][p * 4 + nj][3] += bb.w;
        }

    // ---- LayerNorm stats ----
    #pragma unroll
    for (int mi = 0; mi < 2; ++mi) {
        float s1 = 0.f, s2 = 0.f;
        #pragma unroll
        for (int j = 0; j < 8; ++j)
            #pragma unroll
            for (int r = 0; r < 4; ++r) {
                float v = acc[mi][j][r];
                s1 += v; s2 += v * v;
            }
        s1 += __shfl_xor(s1, 16); s2 += __shfl_xor(s2, 16);
        s1 += __shfl_xor(s1, 32); s2 += __shfl_xor(s2, 32);
        if (quad == 0) {
            stats[wave][0][mi * 16 + ln] = s1;
            stats[wave][1][mi * 16 + ln] = s2;
        }
    }
    __syncthreads();

    float mean[2], rstd[2];
    #pragma unroll
    for (int mi = 0; mi < 2; ++mi) {
        int t = mi * 16 + ln;
        float s1 = stats[0][0][t] + stats[1][0][t] + stats[2][0][t] + stats[3][0][t];
        float s2 = stats[0][1][t] + stats[1][1][t] + stats[2][1][t] + stats[3][1][t];
        mean[mi] = s1 * (1.f / 512.f);
        float var = s2 * (1.f / 512.f) - mean[mi] * mean[mi];
        rstd[mi] = rsqrtf(var + 1e-5f);
    }

    // ---- GELU -> H ----
    #pragma unroll
    for (int p = 0; p < 2; ++p)
        #pragma unroll
        for (int nj = 0; nj < 4; ++nj) {
            int hcol = p * 256 + wave * 64 + nj * 16 + quad * 4;
            float4 gm = *(const float4*)(gamma + hcol);
            float4 bt = *(const float4*)(beta + hcol);
            #pragma unroll
            for (int mi = 0; mi < 2; ++mi) {
                short4v o;
                #pragma unroll
                for (int r = 0; r < 4; ++r) {
                    float g = (r == 0) ? gm.x : (r == 1) ? gm.y : (r == 2) ? gm.z : gm.w;
                    float bta = (r == 0) ? bt.x : (r == 1) ? bt.y : (r == 2) ? bt.z : bt.w;
                    float y = (acc[mi][p * 4 + nj][r] - mean[mi]) * rstd[mi] * g + bta;
                    float u = y * fmaf(y * y, 0.0356774081f, 0.7978845608f);
                    float e = __builtin_amdgcn_exp2f(u * -2.8853900818f);
                    o[r] = f2b(y * __builtin_amdgcn_rcpf(1.f + e));
                }
                *(short4v*)&H[(mi * 16 + ln) * 520 + hcol] = o;
            }
        }

    // ---- phase 2: out = H @ w2^T + b2 + x ----
    f32x4 acc2[2][4];
    #pragma unroll
    for (int i = 0; i < 2; ++i)
        #pragma unroll
        for (int j = 0; j < 4; ++j) acc2[i][j] = {0.f, 0.f, 0.f, 0.f};

    for (int s = 0; s < 8; ++s) {
        const int k0 = s * 64;
        #pragma unroll
        for (int q = 0; q < 4; ++q) {
            *(short8*)&Bs[(br + q * 64) * 72 + bq * 16]     = bp[2 * q];
            *(short8*)&Bs[(br + q * 64) * 72 + bq * 16 + 8] = bp[2 * q + 1];
        }
        __syncthreads();   // also publishes GELU H on s==0
        if (s < 7) loadB(w2, 0, k0 + 64);
        short8 h0[2], h1[2];
        #pragma unroll
        for (int ks = 0; ks < 2; ++ks) {
            h0[ks] = *(const short8*)&H[ln * 520 + k0 + ks * 32 + quad * 8];
            h1[ks] = *(const short8*)&H[(16 + ln) * 520 + k0 + ks * 32 + quad * 8];
        }
        #pragma unroll
        for (int nj = 0; nj < 4; ++nj) {
            #pragma unroll
            for (int ks = 0; ks < 2; ++ks) {
                short8 wf = *(const short8*)&Bs[(wave * 64 + nj * 16 + ln) * 72
                                                + ks * 32 + quad * 8];
                acc2[0][nj] = __builtin_amdgcn_mfma_f32_16x16x32_bf16(
                                  wf, h0[ks], acc2[0][nj], 0, 0, 0);
                acc2[1][nj] = __builtin_amdgcn_mfma_f32_16x16x32_bf16(
                                  wf, h1[ks], acc2[1][nj], 0, 0, 0);
            }
        }
        __syncthreads();
    }

    #pragma unroll
    for (int nj = 0; nj < 4; ++nj) {
        int ocol = wave * 64 + nj * 16 + quad * 4;
        float4 bb = *(const float4*)(b2 + ocol);
        #pragma unroll
        for (int mi = 0; mi < 2; ++mi) {
            int tok = tok0 + mi * 16 + ln;
            const float* xr = (tok < ROWS ? x0 + (size_t)tok * 256
                                          : x1 + (size_t)(tok - ROWS) * 256);
            float4 rv = *(const float4*)(xr + ocol);
            float4 o;
            o.x = acc2[mi][nj][0] + bb.x + rv.x;
            o.y = acc2[mi][nj][1] + bb.y + rv.y;
            o.z = acc2[mi][nj][2] + bb.z + rv.z;
            o.w = acc2[mi][nj][3] + bb.w + rv.w;
            *(float4*)(out + (size_t)tok * 256 + ocol) = o;
        }
    }
}

// ---------------------------------------------------------------------------
extern "C" void kernel_launch(void* const* d_in, const int* in_sizes, int n_in,
                              void* d_out, int out_size, void* d_ws, size_t ws_size,
                              hipStream_t stream)
{
    const float* x0    = (const float*)d_in[0];
    const float* x1    = (const float*)d_in[1];
    const float* Wqk   = (const float*)d_in[2];
    const float* bqk   = (const float*)d_in[3];
    const float* Wv    = (const float*)d_in[4];
    const float* bv    = (const float*)d_in[5];
    const float* Wp    = (const float*)d_in[6];
    const float* bp    = (const float*)d_in[7];
    const float* W1    = (const float*)d_in[8];
    const float* b1    = (const float*)d_in[9];
    const float* gamma = (const float*)d_in[10];
    const float* beta  = (const float*)d_in[11];
    const float* W2    = (const float*)d_in[12];
    const float* b2    = (const float*)d_in[13];
    float* out = (float*)d_out;

    char* ws = (char*)d_ws;
    const size_t MB = 1024 * 1024;
    short* qkb  = (short*)ws;                    // [0,8)
    short* vtb  = (short*)(ws + 8  * MB);        // [8,16)
    short* pO0  = (short*)(ws + 16 * MB);        // [16,24)
    short* pO1  = (short*)(ws + 24 * MB);        // [24,32)
    float* l0   = (float*)(ws + 32 * MB);
    float* l1   = l0 + 16384;
    float* bc   = l1 + 16384;
    short* wq   = (short*)(bc + 512);
    short* wv   = wq + 65536;
    short* w1c  = wv + 65536;                    // [512,512]
    short* w2   = w1c + 262144;                  // [256,512]

    prep<<<1026, 256, 0, stream>>>(Wqk, Wv, Wp, W1, W2, bp, b1,
                                   wq, wv, w1c, w2, bc);
    gemm_qkv<<<dim3(4, 256), 256, 0, stream>>>(x0, x1, wq, wv, bqk, bv, qkb, vtb);
    attn8<<<dim3(16, 16, 4), 256, 0, stream>>>(qkb, vtb, pO0, pO1, l0, l1);
    mlp_fused<<<512, 256, 0, stream>>>(x0, x1, pO0, pO1, l0, l1, w1c, w2, bc,
                                       gamma, beta, b2, out);
}

// Round 5
// 190.938 us; speedup vs baseline: 1.2354x; 1.0231x over previous
//
#include <hip/hip_runtime.h>
#include <hip/hip_bf16.h>
#include <math.h>

typedef __hip_bfloat16 hbf;
typedef __attribute__((ext_vector_type(8))) short short8;
typedef __attribute__((ext_vector_type(4))) short short4v;
typedef __attribute__((ext_vector_type(4))) float f32x4;

#define ROWS 8192
#define SQSL 0.4246609001440095f  // sqrt(SCALE * log2(e)) folded into wq/bqk

__device__ __forceinline__ short f2b(float f) {
    union { hbf h; short s; } u; u.h = __float2bfloat16(f); return u.s;
}
__device__ __forceinline__ float b2f(short s) {
    union { unsigned u; float f; } x;
    x.u = ((unsigned)(unsigned short)s) << 16; return x.f;
}

// ---------------------------------------------------------------------------
// prep_w: only wq (scaled) and wv -- the inputs gemm_qkv needs. 128 blocks.
// The rest of the old prep (w1a copy, w2 copy, W1b@Wp composite, bc) moved
// into gemm_qkv's extra blocks (not needed until mlp_fused, 2 kernels later).
// ---------------------------------------------------------------------------
__global__ __launch_bounds__(256)
void prep_w(const float* __restrict__ Wqk, const float* __restrict__ Wv,
            short* __restrict__ wq, short* __restrict__ wv)
{
    const int bid = blockIdx.x, tid = threadIdx.x;
    const float* src; short* dst; int base; float sc = 1.f;
    if (bid < 64) { src = Wqk; dst = wq; base = bid;      sc = SQSL; }
    else          { src = Wv;  dst = wv; base = bid - 64; }
    int i = base * 256 + tid;
    float4 f = ((const float4*)src)[i];
    short4v s;
    s[0] = f2b(f.x * sc); s[1] = f2b(f.y * sc);
    s[2] = f2b(f.z * sc); s[3] = f2b(f.w * sc);
    *(short4v*)(dst + (size_t)i * 4) = s;
}

// prep-big device path: pbid in [128,1026) with old prep semantics.
__device__ void prep_big(int bid, int tid,
                         const float* __restrict__ Wp, const float* __restrict__ W1,
                         const float* __restrict__ W2, const float* __restrict__ bp,
                         const float* __restrict__ b1,
                         short* __restrict__ w1c, short* __restrict__ w2,
                         float* __restrict__ bc)
{
    if (bid < 384) {
        // W1: keep only cols<256 (W1a) -> w1c[n][0:256]
        int i = (bid - 128) * 256 + tid;
        int n = i >> 7, c = (i & 127) * 4;
        if (c < 256) {
            float4 f = ((const float4*)W1)[i];
            short4v s;
            s[0] = f2b(f.x); s[1] = f2b(f.y); s[2] = f2b(f.z); s[3] = f2b(f.w);
            *(short4v*)(w1c + (size_t)n * 512 + c) = s;
        }
    } else if (bid < 512) {
        int i = (bid - 384) * 256 + tid;
        float4 f = ((const float4*)W2)[i];
        short4v s;
        s[0] = f2b(f.x); s[1] = f2b(f.y); s[2] = f2b(f.z); s[3] = f2b(f.w);
        *(short4v*)(w2 + (size_t)i * 4) = s;
    } else if (bid < 1024) {
        int n = bid - 512;
        const float* wrow = W1 + (size_t)n * 512 + 256;
        float acc = 0.f;
        for (int k = 0; k < 256; ++k)
            acc += wrow[k] * Wp[(size_t)k * 256 + tid];
        w1c[(size_t)n * 512 + 256 + tid] = f2b(acc);
    } else {
        int n = (bid - 1024) * 256 + tid;
        const float* wrow = W1 + (size_t)n * 512 + 256;
        float acc = b1[n];
        for (int k = 0; k < 256; ++k) acc += wrow[k] * bp[k];
        bc[n] = acc;
    }
}

// ---------------------------------------------------------------------------
// QKV GEMM v2 + fused prep-big: blocks <1024 do the measured-good 64x128
// BK=64 LDS-staged GEMM (QK row-major store; V transposed in-LDS -> V^T).
// Blocks >=1024 run prep_big (w1c/w2/bc) -- independent, no LDS/barriers,
// backfill the GEMM tail and remove prep-big + one launch gap from the
// critical path.
// ---------------------------------------------------------------------------
__global__ __launch_bounds__(256)
void gemm_qkv(const float* __restrict__ x0, const float* __restrict__ x1,
              const short* __restrict__ Wa, const short* __restrict__ Wb,
              const float* __restrict__ bias0, const float* __restrict__ bias1,
              short* __restrict__ qkb, short* __restrict__ vtb,
              const float* __restrict__ Wp, const float* __restrict__ W1,
              const float* __restrict__ W2f, const float* __restrict__ bpv,
              const float* __restrict__ b1,
              short* __restrict__ w1c, short* __restrict__ w2c,
              float* __restrict__ bc)
{
    const int bid = blockIdx.x;
    const int tid = threadIdx.x;
    if (bid >= 1024) {
        prep_big(bid - 1024 + 128, tid, Wp, W1, W2f, bpv, b1, w1c, w2c, bc);
        return;
    }
    const int fid  = bid;                              // 0..1023
    const int col0 = (fid >> 8) * 128;                 // XCD = fid%8 ~ row group
    const int row0 = (fid & 255) * 64;
    const int lane = tid & 63, wave = tid >> 6;
    const int ln = lane & 15, quad = lane >> 4;
    const int wm = wave & 1, wn = wave >> 1;

    __shared__ short smem[64 * 72 + 128 * 72];
    short* As = smem;                 // [64][72]
    short* Bs = smem + 64 * 72;       // [128][72]
    short* Vt = smem;                 // epilogue reuse: [128][72] (V blocks)

    const int ar = tid >> 2, ac = tid & 3;   // ar 0..63, ac: 16-col chunk

    f32x4 acc[2][4];
    #pragma unroll
    for (int i = 0; i < 2; ++i)
        #pragma unroll
        for (int j = 0; j < 4; ++j) acc[i][j] = {0.f, 0.f, 0.f, 0.f};

    const short* wbase = (col0 < 256) ? Wa + (size_t)col0 * 256
                                      : Wb + (size_t)(col0 - 256) * 256;
    const float* xrow = (row0 + ar < ROWS)
        ? x0 + (size_t)(row0 + ar) * 256
        : x1 + (size_t)(row0 + ar - ROWS) * 256;

    float4 aF[4];
    short8 bR[4];
    #pragma unroll
    for (int i = 0; i < 4; ++i) aF[i] = ((const float4*)(xrow + ac * 16))[i];
    bR[0] = *(const short8*)(wbase + (size_t)ar * 256 + ac * 16);
    bR[1] = *(const short8*)(wbase + (size_t)ar * 256 + ac * 16 + 8);
    bR[2] = *(const short8*)(wbase + (size_t)(ar + 64) * 256 + ac * 16);
    bR[3] = *(const short8*)(wbase + (size_t)(ar + 64) * 256 + ac * 16 + 8);

    for (int k0 = 0; k0 < 256; k0 += 64) {
        {
            short8 s0, s1;
            s0[0] = f2b(aF[0].x); s0[1] = f2b(aF[0].y); s0[2] = f2b(aF[0].z); s0[3] = f2b(aF[0].w);
            s0[4] = f2b(aF[1].x); s0[5] = f2b(aF[1].y); s0[6] = f2b(aF[1].z); s0[7] = f2b(aF[1].w);
            s1[0] = f2b(aF[2].x); s1[1] = f2b(aF[2].y); s1[2] = f2b(aF[2].z); s1[3] = f2b(aF[2].w);
            s1[4] = f2b(aF[3].x); s1[5] = f2b(aF[3].y); s1[6] = f2b(aF[3].z); s1[7] = f2b(aF[3].w);
            *(short8*)&As[ar * 72 + ac * 16]     = s0;
            *(short8*)&As[ar * 72 + ac * 16 + 8] = s1;
        }
        *(short8*)&Bs[ar * 72 + ac * 16]            = bR[0];
        *(short8*)&Bs[ar * 72 + ac * 16 + 8]        = bR[1];
        *(short8*)&Bs[(ar + 64) * 72 + ac * 16]     = bR[2];
        *(short8*)&Bs[(ar + 64) * 72 + ac * 16 + 8] = bR[3];
        __syncthreads();

        if (k0 + 64 < 256) {
            const int kk = k0 + 64 + ac * 16;
            #pragma unroll
            for (int i = 0; i < 4; ++i) aF[i] = ((const float4*)(xrow + kk))[i];
            bR[0] = *(const short8*)(wbase + (size_t)ar * 256 + kk);
            bR[1] = *(const short8*)(wbase + (size_t)ar * 256 + kk + 8);
            bR[2] = *(const short8*)(wbase + (size_t)(ar + 64) * 256 + kk);
            bR[3] = *(const short8*)(wbase + (size_t)(ar + 64) * 256 + kk + 8);
        }

        short8 a[2][2], b[4][2];
        #pragma unroll
        for (int mi = 0; mi < 2; ++mi)
            #pragma unroll
            for (int ks = 0; ks < 2; ++ks)
                a[mi][ks] = *(const short8*)&As[(wm * 32 + mi * 16 + ln) * 72 + ks * 32 + quad * 8];
        #pragma unroll
        for (int nj = 0; nj < 4; ++nj)
            #pragma unroll
            for (int ks = 0; ks < 2; ++ks)
                b[nj][ks] = *(const short8*)&Bs[(wn * 64 + nj * 16 + ln) * 72 + ks * 32 + quad * 8];
        #pragma unroll
        for (int mi = 0; mi < 2; ++mi)
            #pragma unroll
            for (int nj = 0; nj < 4; ++nj) {
                acc[mi][nj] = __builtin_amdgcn_mfma_f32_16x16x32_bf16(
                                  b[nj][0], a[mi][0], acc[mi][nj], 0, 0, 0);
                acc[mi][nj] = __builtin_amdgcn_mfma_f32_16x16x32_bf16(
                                  b[nj][1], a[mi][1], acc[mi][nj], 0, 0, 0);
            }
        __syncthreads();
    }

    if (col0 < 256) {
        // QK path: row-major store with SQSL-scaled bias
        #pragma unroll
        for (int nj = 0; nj < 4; ++nj) {
            const int wcol = col0 + wn * 64 + nj * 16 + quad * 4;
            float4 bb = *(const float4*)(bias0 + wcol);
            #pragma unroll
            for (int mi = 0; mi < 2; ++mi) {
                const int tok = row0 + wm * 32 + mi * 16 + ln;
                f32x4 v = acc[mi][nj];
                short4v o;
                o[0] = f2b(fmaf(bb.x, SQSL, v[0]));
                o[1] = f2b(fmaf(bb.y, SQSL, v[1]));
                o[2] = f2b(fmaf(bb.z, SQSL, v[2]));
                o[3] = f2b(fmaf(bb.w, SQSL, v[3]));
                *(short4v*)(qkb + (size_t)tok * 256 + wcol) = o;
            }
        }
    } else {
        // V path: bias add -> LDS transpose -> direct V^T store (vtrans fused)
        #pragma unroll
        for (int nj = 0; nj < 4; ++nj) {
            const int wrel = wn * 64 + nj * 16 + quad * 4;
            float4 bb = *(const float4*)(bias1 + (col0 - 256) + wrel);
            #pragma unroll
            for (int mi = 0; mi < 2; ++mi) {
                const int tl = wm * 32 + mi * 16 + ln;
                f32x4 v = acc[mi][nj];
                Vt[(wrel + 0) * 72 + tl] = f2b(v[0] + bb.x);
                Vt[(wrel + 1) * 72 + tl] = f2b(v[1] + bb.y);
                Vt[(wrel + 2) * 72 + tl] = f2b(v[2] + bb.z);
                Vt[(wrel + 3) * 72 + tl] = f2b(v[3] + bb.w);
            }
        }
        __syncthreads();
        {
            const int g4 = (row0 >> 11) * 4, tc0 = row0 & 2047;
            const int r = tid >> 1, hf = tid & 1;
            const int vcol = (col0 - 256) + r;          // 0..255
            const int hh = vcol >> 6, d = vcol & 63;
            short* dst = vtb + (size_t)((g4 + hh) * 64 + d) * 2048 + tc0 + hf * 32;
            #pragma unroll
            for (int cc = 0; cc < 4; ++cc)
                *(short8*)(dst + cc * 8) = *(const short8*)&Vt[r * 72 + hf * 32 + cc * 8];
        }
    }
}

// ---------------------------------------------------------------------------
// MFMA flash cross-attention v10 (r3 measured-best, exact revert): 2 waves x
// 64 q-rows, no setprio, no COFF (cancels in O/l), v_perm bf16 pack, l via
// MFMA-against-ones. r4 proved frag amortization > occupancy here.
// ---------------------------------------------------------------------------
__global__ __launch_bounds__(128, 2)
void attn8(const short* __restrict__ qkb, const short* __restrict__ vtbuf,
           short* __restrict__ pO0, short* __restrict__ pO1,
           float* __restrict__ l0, float* __restrict__ l1)
{
    const int nfl = blockIdx.x + (blockIdx.y << 4) + (blockIdx.z << 8);
    const int qt  = nfl >> 6;               // 0..15
    const int gg  = nfl & 63;               // group: id % 8 == gg % 8 -> XCD
    const int b    = (gg >> 2) & 3, h = gg & 3;
    const int dir  = gg >> 5;
    const int half = (gg >> 4) & 1;
    const int tid = threadIdx.x;
    const int lane = tid & 63, wave = tid >> 6;   // wave 0/1
    const int ln   = lane & 15, quad = lane >> 4;

    const int qbase = dir * ROWS + b * 2048;
    const int kbase = (1 - dir) * ROWS + b * 2048;
    const int vg    = ((1 - dir) * 4 + b) * 4 + h;
    const int jlo   = half * 1024, jhi = jlo + 1024;

    short* __restrict__ pO = half ? pO1 : pO0;
    float* __restrict__ lb = half ? l1  : l0;

    __shared__ short QP[128 * 72];   // Q tile then P tile (per-wave rows)
    __shared__ short KS[64 * 72];
    __shared__ short VT[64 * 72];

    const int c = tid & 7, r0 = tid >> 3;   // r0: 0..15
    #pragma unroll
    for (int g = 0; g < 8; ++g) {
        int r = r0 + g * 16;
        *(short8*)&QP[r * 72 + c * 8] =
            *(const short8*)(qkb + (size_t)(qbase + qt * 128 + r) * 256 + h * 64 + c * 8);
    }
    #pragma unroll
    for (int g = 0; g < 4; ++g) {
        int r = r0 + g * 16;
        *(short8*)&KS[r * 72 + c * 8] =
            *(const short8*)(qkb + (size_t)(kbase + jlo + r) * 256 + h * 64 + c * 8);
        *(short8*)&VT[r * 72 + c * 8] =
            *(const short8*)(vtbuf + (size_t)(vg * 64 + r) * 2048 + jlo + c * 8);
    }
    __syncthreads();

    short8 qf[4][2];
    #pragma unroll
    for (int mi = 0; mi < 4; ++mi)
        #pragma unroll
        for (int ks = 0; ks < 2; ++ks)
            qf[mi][ks] = *(const short8*)&QP[(wave * 64 + mi * 16 + ln) * 72
                                             + ks * 32 + quad * 8];

    short8 ones;
    #pragma unroll
    for (int j = 0; j < 8; ++j) ones[j] = (short)0x3F80;   // bf16 1.0

    f32x4 Ot[4][4];
    #pragma unroll
    for (int mi = 0; mi < 4; ++mi)
        #pragma unroll
        for (int dt = 0; dt < 4; ++dt) Ot[mi][dt] = {0.f, 0.f, 0.f, 0.f};
    f32x4 lacc[4];
    #pragma unroll
    for (int mi = 0; mi < 4; ++mi) lacc[mi] = {0.f, 0.f, 0.f, 0.f};

    for (int j0 = jlo; j0 < jhi; j0 += 64) {
        short8 kreg[4], vreg[4];
        const bool more = (j0 + 64) < jhi;
        if (more) {
            #pragma unroll
            for (int g = 0; g < 4; ++g) {
                int r = r0 + g * 16;
                kreg[g] = *(const short8*)(qkb + (size_t)(kbase + j0 + 64 + r) * 256
                                           + h * 64 + c * 8);
                vreg[g] = *(const short8*)(vtbuf + (size_t)(vg * 64 + r) * 2048
                                           + j0 + 64 + c * 8);
            }
        }

        // S^T = K @ Q^T   (K frags shared across 4 q-subtiles)
        f32x4 St[4][4];
        #pragma unroll
        for (int t = 0; t < 4; ++t) {
            short8 k0 = *(const short8*)&KS[(t * 16 + ln) * 72 + quad * 8];
            short8 k1 = *(const short8*)&KS[(t * 16 + ln) * 72 + 32 + quad * 8];
            #pragma unroll
            for (int mi = 0; mi < 4; ++mi) {
                f32x4 z = {0.f, 0.f, 0.f, 0.f};
                z = __builtin_amdgcn_mfma_f32_16x16x32_bf16(k0, qf[mi][0], z, 0, 0, 0);
                St[mi][t] = __builtin_amdgcn_mfma_f32_16x16x32_bf16(k1, qf[mi][1], z, 0, 0, 0);
            }
        }

        // p = exp2(St); v_perm truncation-pack; P -> own QP rows
        #pragma unroll
        for (int mi = 0; mi < 4; ++mi)
            #pragma unroll
            for (int t = 0; t < 4; ++t) {
                float p0 = __builtin_amdgcn_exp2f(St[mi][t][0]);
                float p1 = __builtin_amdgcn_exp2f(St[mi][t][1]);
                float p2 = __builtin_amdgcn_exp2f(St[mi][t][2]);
                float p3 = __builtin_amdgcn_exp2f(St[mi][t][3]);
                unsigned d0 = __builtin_amdgcn_perm(__float_as_uint(p1),
                                                    __float_as_uint(p0), 0x07060302u);
                unsigned d1 = __builtin_amdgcn_perm(__float_as_uint(p3),
                                                    __float_as_uint(p2), 0x07060302u);
                *(int2*)&QP[(wave * 64 + mi * 16 + ln) * 72 + t * 16 + quad * 4] =
                    make_int2((int)d0, (int)d1);
            }

        // reload P as B-frags; l += 1*P via MFMA; O^T += V^T @ P^T
        short8 pa[4][2];
        #pragma unroll
        for (int mi = 0; mi < 4; ++mi)
            #pragma unroll
            for (int ks = 0; ks < 2; ++ks)
                pa[mi][ks] = *(const short8*)&QP[(wave * 64 + mi * 16 + ln) * 72
                                                 + ks * 32 + quad * 8];
        #pragma unroll
        for (int mi = 0; mi < 4; ++mi) {
            lacc[mi] = __builtin_amdgcn_mfma_f32_16x16x32_bf16(
                           ones, pa[mi][0], lacc[mi], 0, 0, 0);
            lacc[mi] = __builtin_amdgcn_mfma_f32_16x16x32_bf16(
                           ones, pa[mi][1], lacc[mi], 0, 0, 0);
        }
        #pragma unroll
        for (int dt = 0; dt < 4; ++dt) {
            short8 v0 = *(const short8*)&VT[(dt * 16 + ln) * 72 + quad * 8];
            short8 v1 = *(const short8*)&VT[(dt * 16 + ln) * 72 + 32 + quad * 8];
            #pragma unroll
            for (int mi = 0; mi < 4; ++mi) {
                Ot[mi][dt] = __builtin_amdgcn_mfma_f32_16x16x32_bf16(
                                 v0, pa[mi][0], Ot[mi][dt], 0, 0, 0);
                Ot[mi][dt] = __builtin_amdgcn_mfma_f32_16x16x32_bf16(
                                 v1, pa[mi][1], Ot[mi][dt], 0, 0, 0);
            }
        }
        __syncthreads();

        if (more) {
            #pragma unroll
            for (int g = 0; g < 4; ++g) {
                int r = r0 + g * 16;
                *(short8*)&KS[r * 72 + c * 8] = kreg[g];
                *(short8*)&VT[r * 72 + c * 8] = vreg[g];
            }
        }
        __syncthreads();
    }

    #pragma unroll
    for (int mi = 0; mi < 4; ++mi) {
        int tok = qbase + qt * 128 + wave * 64 + mi * 16 + ln;
        if (quad == 0) lb[tok] = lacc[mi][0];
        #pragma unroll
        for (int dt = 0; dt < 4; ++dt) {
            short4v o;
            #pragma unroll
            for (int r = 0; r < 4; ++r) o[r] = f2b(Ot[mi][dt][r]);
            *(short4v*)(pO + (size_t)tok * 256 + h * 64 + dt * 16 + quad * 4) = o;
        }
    }
}

// ---------------------------------------------------------------------------
// Fused MLP v2 (r1/r3 measured-good): [x|m] staged ONCE into H, BK=64 in both
// phases, B-tile register prefetch through LDS bounce.
// ---------------------------------------------------------------------------
__global__ __launch_bounds__(256)
void mlp_fused(const float* __restrict__ x0, const float* __restrict__ x1,
               const short* __restrict__ pO0, const short* __restrict__ pO1,
               const float* __restrict__ l0, const float* __restrict__ l1,
               const short* __restrict__ w1c, const short* __restrict__ w2,
               const float* __restrict__ bc, const float* __restrict__ gamma,
               const float* __restrict__ beta, const float* __restrict__ b2,
               float* __restrict__ out)
{
    const int tok0 = blockIdx.x * 32;
    const int tid = threadIdx.x;
    const int lane = tid & 63, wave = tid >> 6;
    const int ln = lane & 15, quad = lane >> 4;

    __shared__ short H [32 * 520];    // [x|m] input, later GELU activations
    __shared__ short Bs[256 * 72];    // weight K-panel (both phases)
    __shared__ float stats[4][2][32];

    const int br = tid >> 2, bq = tid & 3;
    short8 bp[8];
    auto loadB = [&](const short* W, int rw, int k0) {
        const short* src = W + (size_t)(rw + br) * 512 + k0 + bq * 16;
        #pragma unroll
        for (int q = 0; q < 4; ++q) {
            bp[2 * q]     = *(const short8*)(src + (size_t)q * 64 * 512);
            bp[2 * q + 1] = *(const short8*)(src + (size_t)q * 64 * 512 + 8);
        }
    };
    loadB(w1c, 0, 0);   // section (k2=0, p=0)

    // ---- stage A = [x | m] into H (once) ----
    {
        const int arow = tid >> 3, ac = tid & 7;   // ac: 64-col block
        const int tok = tok0 + arow;
        if (ac < 4) {
            const float* xr = (tok < ROWS ? x0 + (size_t)tok * 256
                                          : x1 + (size_t)(tok - ROWS) * 256) + ac * 64;
            #pragma unroll
            for (int cc = 0; cc < 8; ++cc) {
                float4 f0 = ((const float4*)(xr + cc * 8))[0];
                float4 f1 = ((const float4*)(xr + cc * 8))[1];
                short8 s;
                s[0] = f2b(f0.x); s[1] = f2b(f0.y); s[2] = f2b(f0.z); s[3] = f2b(f0.w);
                s[4] = f2b(f1.x); s[5] = f2b(f1.y); s[6] = f2b(f1.z); s[7] = f2b(f1.w);
                *(short8*)&H[arow * 520 + ac * 64 + cc * 8] = s;
            }
        } else {
            const int vc = (ac - 4) * 64;
            const float inv = __builtin_amdgcn_rcpf(l0[tok] + l1[tok]);
            #pragma unroll
            for (int cc = 0; cc < 8; ++cc) {
                short8 a = *(const short8*)(pO0 + (size_t)tok * 256 + vc + cc * 8);
                short8 b = *(const short8*)(pO1 + (size_t)tok * 256 + vc + cc * 8);
                short8 s;
                #pragma unroll
                for (int j = 0; j < 8; ++j)
                    s[j] = f2b((b2f(a[j]) + b2f(b[j])) * inv);
                *(short8*)&H[arow * 520 + 256 + vc + cc * 8] = s;
            }
        }
    }

    f32x4 acc[2][8];
    #pragma unroll
    for (int i = 0; i < 2; ++i)
        #pragma unroll
        for (int j = 0; j < 8; ++j) acc[i][j] = {0.f, 0.f, 0.f, 0.f};

    __syncthreads();   // H ready

    // ---- phase 1: h = [x|m] @ w1c^T ----
    for (int k2 = 0; k2 < 8; ++k2) {
        const int k0 = k2 * 64;
        short8 a0[2], a1[2];
        #pragma unroll
        for (int ks = 0; ks < 2; ++ks) {
            a0[ks] = *(const short8*)&H[ln * 520 + k0 + ks * 32 + quad * 8];
            a1[ks] = *(const short8*)&H[(16 + ln) * 520 + k0 + ks * 32 + quad * 8];
        }
        #pragma unroll
        for (int p = 0; p < 2; ++p) {
            #pragma unroll
            for (int q = 0; q < 4; ++q) {
                *(short8*)&Bs[(br + q * 64) * 72 + bq * 16]     = bp[2 * q];
                *(short8*)&Bs[(br + q * 64) * 72 + bq * 16 + 8] = bp[2 * q + 1];
            }
            __syncthreads();
            if (p == 0)          loadB(w1c, 256, k0);
            else if (k2 < 7)     loadB(w1c, 0, k0 + 64);
            #pragma unroll
            for (int nj = 0; nj < 4; ++nj) {
                #pragma unroll
                for (int ks = 0; ks < 2; ++ks) {
                    short8 bf = *(const short8*)&Bs[(wave * 64 + nj * 16 + ln) * 72
                                                    + ks * 32 + quad * 8];
                    acc[0][p * 4 + nj] = __builtin_amdgcn_mfma_f32_16x16x32_bf16(
                                             bf, a0[ks], acc[0][p * 4 + nj], 0, 0, 0);
                    acc[1][p * 4 + nj] = __builtin_amdgcn_mfma_f32_16x16x32_bf16(
                                             bf, a1[ks], acc[1][p * 4 + nj], 0, 0, 0);
                }
            }
            __syncthreads();
        }
    }

    loadB(w2, 0, 0);   // prefetch first w2 panel under LN/GELU

    // add bc before LN stats
    #pragma unroll
    for (int p = 0; p < 2; ++p)
        #pragma unroll
        for (int nj = 0; nj < 4; ++nj) {
            int hcol = p * 256 + wave * 64 + nj * 16 + quad * 4;
            float4 bb = *(const float4*)(bc + hcol);
            acc[0][p * 4 + nj][0] += bb.x; acc[1][p * 4 + nj][0] += bb.x;
            acc[0][p * 4 + nj][1] += bb.y; acc[1][p * 4 + nj][1] += bb.y;
            acc[0][p * 4 + nj][2] += bb.z; acc[1][p * 4 + nj][2] += bb.z;
            acc[0][p * 4 + nj][3] += bb.w; acc[1][p * 4 + nj][3] += bb.w;
        }

    // ---- LayerNorm stats ----
    #pragma unroll
    for (int mi = 0; mi < 2; ++mi) {
        float s1 = 0.f, s2 = 0.f;
        #pragma unroll
        for (int j = 0; j < 8; ++j)
            #pragma unroll
            for (int r = 0; r < 4; ++r) {
                float v = acc[mi][j][r];
                s1 += v; s2 += v * v;
            }
        s1 += __shfl_xor(s1, 16); s2 += __shfl_xor(s2, 16);
        s1 += __shfl_xor(s1, 32); s2 += __shfl_xor(s2, 32);
        if (quad == 0) {
            stats[wave][0][mi * 16 + ln] = s1;
            stats[wave][1][mi * 16 + ln] = s2;
        }
    }
    __syncthreads();

    float mean[2], rstd[2];
    #pragma unroll
    for (int mi = 0; mi < 2; ++mi) {
        int t = mi * 16 + ln;
        float s1 = stats[0][0][t] + stats[1][0][t] + stats[2][0][t] + stats[3][0][t];
        float s2 = stats[0][1][t] + stats[1][1][t] + stats[2][1][t] + stats[3][1][t];
        mean[mi] = s1 * (1.f / 512.f);
        float var = s2 * (1.f / 512.f) - mean[mi] * mean[mi];
        rstd[mi] = rsqrtf(var + 1e-5f);
    }

    // ---- GELU -> H ----
    #pragma unroll
    for (int p = 0; p < 2; ++p)
        #pragma unroll
        for (int nj = 0; nj < 4; ++nj) {
            int hcol = p * 256 + wave * 64 + nj * 16 + quad * 4;
            float4 gm = *(const float4*)(gamma + hcol);
            float4 bt = *(const float4*)(beta + hcol);
            #pragma unroll
            for (int mi = 0; mi < 2; ++mi) {
                short4v o;
                #pragma unroll
                for (int r = 0; r < 4; ++r) {
                    float g = (r == 0) ? gm.x : (r == 1) ? gm.y : (r == 2) ? gm.z : gm.w;
                    float bta = (r == 0) ? bt.x : (r == 1) ? bt.y : (r == 2) ? bt.z : bt.w;
                    float y = (acc[mi][p * 4 + nj][r] - mean[mi]) * rstd[mi] * g + bta;
                    float u = y * fmaf(y * y, 0.0356774081f, 0.7978845608f);
                    float e = __builtin_amdgcn_exp2f(u * -2.8853900818f);
                    o[r] = f2b(y * __builtin_amdgcn_rcpf(1.f + e));
                }
                *(short4v*)&H[(mi * 16 + ln) * 520 + hcol] = o;
            }
        }

    // ---- phase 2: out = H @ w2^T + b2 + x ----
    f32x4 acc2[2][4];
    #pragma unroll
    for (int i = 0; i < 2; ++i)
        #pragma unroll
        for (int j = 0; j < 4; ++j) acc2[i][j] = {0.f, 0.f, 0.f, 0.f};

    for (int s = 0; s < 8; ++s) {
        const int k0 = s * 64;
        #pragma unroll
        for (int q = 0; q < 4; ++q) {
            *(short8*)&Bs[(br + q * 64) * 72 + bq * 16]     = bp[2 * q];
            *(short8*)&Bs[(br + q * 64) * 72 + bq * 16 + 8] = bp[2 * q + 1];
        }
        __syncthreads();   // also publishes GELU H on s==0
        if (s < 7) loadB(w2, 0, k0 + 64);
        short8 h0[2], h1[2];
        #pragma unroll
        for (int ks = 0; ks < 2; ++ks) {
            h0[ks] = *(const short8*)&H[ln * 520 + k0 + ks * 32 + quad * 8];
            h1[ks] = *(const short8*)&H[(16 + ln) * 520 + k0 + ks * 32 + quad * 8];
        }
        #pragma unroll
        for (int nj = 0; nj < 4; ++nj) {
            #pragma unroll
            for (int ks = 0; ks < 2; ++ks) {
                short8 wf = *(const short8*)&Bs[(wave * 64 + nj * 16 + ln) * 72
                                                + ks * 32 + quad * 8];
                acc2[0][nj] = __builtin_amdgcn_mfma_f32_16x16x32_bf16(
                                  wf, h0[ks], acc2[0][nj], 0, 0, 0);
                acc2[1][nj] = __builtin_amdgcn_mfma_f32_16x16x32_bf16(
                                  wf, h1[ks], acc2[1][nj], 0, 0, 0);
            }
        }
        __syncthreads();
    }

    #pragma unroll
    for (int nj = 0; nj < 4; ++nj) {
        int ocol = wave * 64 + nj * 16 + quad * 4;
        float4 bb = *(const float4*)(b2 + ocol);
        #pragma unroll
        for (int mi = 0; mi < 2; ++mi) {
            int tok = tok0 + mi * 16 + ln;
            const float* xr = (tok < ROWS ? x0 + (size_t)tok * 256
                                          : x1 + (size_t)(tok - ROWS) * 256);
            float4 rv = *(const float4*)(xr + ocol);
            float4 o;
            o.x = acc2[mi][nj][0] + bb.x + rv.x;
            o.y = acc2[mi][nj][1] + bb.y + rv.y;
            o.z = acc2[mi][nj][2] + bb.z + rv.z;
            o.w = acc2[mi][nj][3] + bb.w + rv.w;
            *(float4*)(out + (size_t)tok * 256 + ocol) = o;
        }
    }
}

// ---------------------------------------------------------------------------
extern "C" void kernel_launch(void* const* d_in, const int* in_sizes, int n_in,
                              void* d_out, int out_size, void* d_ws, size_t ws_size,
                              hipStream_t stream)
{
    const float* x0    = (const float*)d_in[0];
    const float* x1    = (const float*)d_in[1];
    const float* Wqk   = (const float*)d_in[2];
    const float* bqk   = (const float*)d_in[3];
    const float* Wv    = (const float*)d_in[4];
    const float* bv    = (const float*)d_in[5];
    const float* Wp    = (const float*)d_in[6];
    const float* bp    = (const float*)d_in[7];
    const float* W1    = (const float*)d_in[8];
    const float* b1    = (const float*)d_in[9];
    const float* gamma = (const float*)d_in[10];
    const float* beta  = (const float*)d_in[11];
    const float* W2    = (const float*)d_in[12];
    const float* b2    = (const float*)d_in[13];
    float* out = (float*)d_out;

    char* ws = (char*)d_ws;
    const size_t MB = 1024 * 1024;
    short* qkb  = (short*)ws;                    // [0,8)
    short* vtb  = (short*)(ws + 8  * MB);        // [8,16)
    short* pO0  = (short*)(ws + 16 * MB);        // [16,24)
    short* pO1  = (short*)(ws + 24 * MB);        // [24,32)
    float* l0   = (float*)(ws + 32 * MB);
    float* l1   = l0 + 16384;
    float* bc   = l1 + 16384;
    short* wq   = (short*)(bc + 512);
    short* wv   = wq + 65536;
    short* w1c  = wv + 65536;                    // [512,512]
    short* w2   = w1c + 262144;                  // [256,512]

    prep_w<<<128, 256, 0, stream>>>(Wqk, Wv, wq, wv);
    gemm_qkv<<<1922, 256, 0, stream>>>(x0, x1, wq, wv, bqk, bv, qkb, vtb,
                                       Wp, W1, W2, bp, b1, w1c, w2, bc);
    attn8<<<dim3(16, 16, 4), 128, 0, stream>>>(qkb, vtb, pO0, pO1, l0, l1);
    mlp_fused<<<512, 256, 0, stream>>>(x0, x1, pO0, pO1, l0, l1, w1c, w2, bc,
                                       gamma, beta, b2, out);
}